// Round 5
// baseline (216.632 us; speedup 1.0000x reference)
//
#include <hip/hip_runtime.h>

#define NN 100000
#define NE 3200000
#define FIN 256
#define H1 8
#define C2 16
#define NEG 0.2f

#define BKT 64                        // dst nodes per fine bucket
#define NB 1563                       // fine buckets with real nodes
#define NBP 1568                      // padded fine buckets (32 supers * 49)
#define CAP 2560                      // max edges per fine bucket (mean 2048)
#define SB 32                         // super-buckets
#define SBN 3136                      // nodes per super (49 * 64)
#define FPS 49                        // fine buckets per super
#define SCAP 110000                   // super region capacity (mean 100000)
#define EPB1 12500                    // NE / 256
#define P2CAP 13760                   // >= ceil(SCAP/8)

// ---- layer-1 linear: xl1 = x@Wl1+bl1, xr1 = x@Wr1+br1 (one thread/node) ----
__global__ __launch_bounds__(256) void k_lin1(
        const float* __restrict__ x,
        const float* __restrict__ Wl, const float* __restrict__ bl,
        const float* __restrict__ Wr, const float* __restrict__ br,
        float* __restrict__ xl1, float* __restrict__ xr1) {
    int n = blockIdx.x * 256 + threadIdx.x;
    if (n >= NN) return;
    float accl[H1], accr[H1];
    #pragma unroll
    for (int h = 0; h < H1; ++h) { accl[h] = bl[h]; accr[h] = br[h]; }
    const float4* xrow = (const float4*)(x + (size_t)n * FIN);
    for (int j = 0; j < FIN / 4; ++j) {
        float4 v = xrow[j];
        float xv[4] = {v.x, v.y, v.z, v.w};
        #pragma unroll
        for (int q = 0; q < 4; ++q) {
            int f = j * 4 + q;
            #pragma unroll
            for (int h = 0; h < H1; ++h) {
                accl[h] = fmaf(xv[q], Wl[f * H1 + h], accl[h]);
                accr[h] = fmaf(xv[q], Wr[f * H1 + h], accr[h]);
            }
        }
    }
    #pragma unroll
    for (int h = 0; h < H1; ++h) {
        xl1[(size_t)n * H1 + h] = accl[h];
        xr1[(size_t)n * H1 + h] = accr[h];
    }
}

// ---- partition stage 1: edges -> 32 super-buckets, LDS sort, coalesced flush
__global__ __launch_bounds__(512) void k_p1(const int* __restrict__ ei,
                                            int* __restrict__ gcur1,
                                            int* __restrict__ sup1) {
    __shared__ int buf[EPB1];
    __shared__ int cnt[SB], nb[SB], cnt2[SB], gb[SB];
    int tid = threadIdx.x;
    int base = blockIdx.x * EPB1;
    if (tid < SB) { cnt[tid] = 0; cnt2[tid] = 0; }
    __syncthreads();
    for (int i = tid; i < EPB1; i += 512)
        atomicAdd(&cnt[ei[NE + base + i] / SBN], 1);
    __syncthreads();
    if (tid < SB) {                       // exclusive scan (one wave) + reserve
        int v = cnt[tid], inc = v;
        #pragma unroll
        for (int off = 1; off < SB; off <<= 1) {
            int u = __shfl_up(inc, off, 64);
            if (tid >= off) inc += u;
        }
        nb[tid] = inc - v;
        gb[tid] = atomicAdd(&gcur1[tid], v);
    }
    __syncthreads();
    for (int i = tid; i < EPB1; i += 512) {
        int src = ei[base + i];
        int dst = ei[NE + base + i];
        int s = dst / SBN;
        int r = dst - s * SBN;
        int k = atomicAdd(&cnt2[s], 1);
        buf[nb[s] + k] = (r << 17) | src;
    }
    __syncthreads();
    for (int s = 0; s < SB; ++s) {        // coalesced run flush
        int c = cnt[s], b = gb[s], o = nb[s];
        size_t dbase = (size_t)s * SCAP + b;
        for (int i = tid; i < c; i += 512)
            if (b + i < SCAP) sup1[dbase + i] = buf[o + i];
    }
}

// ---- partition stage 2: super-bucket slice -> 49 fine buckets ----
__global__ __launch_bounds__(512) void k_p2(const int* __restrict__ sup1,
                                            const int* __restrict__ gcur1,
                                            int* __restrict__ gcur2,
                                            int* __restrict__ bedges) {
    __shared__ int buf[P2CAP];
    __shared__ int cnt[FPS], nb[FPS], cnt2[FPS], gb[FPS];
    int s   = blockIdx.x >> 3;
    int sub = blockIdx.x & 7;
    int tid = threadIdx.x;
    int total = gcur1[s]; if (total > SCAP) total = SCAP;
    int beg = (int)((long)total * sub / 8);
    int end = (int)((long)total * (sub + 1) / 8);
    int n = end - beg;
    const int* sp = sup1 + (size_t)s * SCAP + beg;
    if (tid < FPS) { cnt[tid] = 0; cnt2[tid] = 0; }
    __syncthreads();
    for (int i = tid; i < n; i += 512)
        atomicAdd(&cnt[(sp[i] >> 17) >> 6], 1);
    __syncthreads();
    if (tid < 64) {                       // exclusive scan (one wave) + reserve
        int v = (tid < FPS) ? cnt[tid] : 0, inc = v;
        #pragma unroll
        for (int off = 1; off < 64; off <<= 1) {
            int u = __shfl_up(inc, off, 64);
            if (tid >= off) inc += u;
        }
        if (tid < FPS) {
            nb[tid] = inc - v;
            gb[tid] = atomicAdd(&gcur2[s * FPS + tid], v);
        }
    }
    __syncthreads();
    for (int i = tid; i < n; i += 512) {
        int pk = sp[i];
        int fb = (pk >> 17) >> 6;
        int k = atomicAdd(&cnt2[fb], 1);
        buf[nb[fb] + k] = (((pk >> 17) & 63) << 17) | (pk & 0x1FFFF);
    }
    __syncthreads();
    for (int fb = 0; fb < FPS; ++fb) {    // coalesced run flush
        int c = cnt[fb], b = gb[fb], o = nb[fb];
        size_t dbase = (size_t)(s * FPS + fb) * CAP + b;
        for (int i = tid; i < c; i += 512)
            if (b + i < CAP) bedges[dbase + i] = buf[o + i];
    }
}

// ---- GATv2 layer, block-per-bucket, quad-of-lanes-per-edge ----
template<int D, bool FUSE_MID>
__global__ __launch_bounds__(256) void k_gat3(
        const int* __restrict__ bedges, const int* __restrict__ gcur,
        const float* __restrict__ xl, const float* __restrict__ xr,
        const float* __restrict__ att, const float* __restrict__ bias,
        const float* __restrict__ Wl2, const float* __restrict__ bl2,
        const float* __restrict__ Wr2, const float* __restrict__ br2,
        float* __restrict__ out, float* __restrict__ out2) {
    constexpr int LPE = D / 4;     // lanes per edge
    constexpr int EPC = 64 / LPE;  // edges per chunk
    constexpr int RC  = LPE;       // register chunks covering 64 edges

    __shared__ int sorted[CAP];
    __shared__ int hist[BKT], nbase[BKT], scnt[BKT];
    int bkt = blockIdx.x;
    int tid = threadIdx.x;
    int ecnt = gcur[bkt]; if (ecnt > CAP) ecnt = CAP;
    const int* be = bedges + (size_t)bkt * CAP;
    if (tid < BKT) { hist[tid] = 0; scnt[tid] = 0; }
    __syncthreads();
    for (int i = tid; i < ecnt; i += 256)
        atomicAdd(&hist[be[i] >> 17], 1);
    __syncthreads();
    if (tid < BKT) {                       // wave-parallel exclusive scan
        int v = hist[tid];
        int inc = v;
        #pragma unroll
        for (int off = 1; off < 64; off <<= 1) {
            int u = __shfl_up(inc, off, 64);
            if (tid >= off) inc += u;
        }
        nbase[tid] = inc - v;
    }
    __syncthreads();
    for (int i = tid; i < ecnt; i += 256) {
        int pk = be[i];
        int dl = pk >> 17;
        int r = atomicAdd(&scnt[dl], 1);
        sorted[nbase[dl] + r] = pk & 0x1FFFF;
    }
    __syncthreads();

    int wave = tid >> 6, lane = tid & 63;
    int q  = lane & (LPE - 1);
    int eo = lane / LPE;

    float attq[4], biasq[4];
    #pragma unroll
    for (int j = 0; j < 4; ++j) { attq[j] = att[q * 4 + j]; biasq[j] = bias[q * 4 + j]; }
    float wl2c[H1], wr2c[H1], bl2c = 0.f, br2c = 0.f;
    if (FUSE_MID && lane < C2) {
        #pragma unroll
        for (int d = 0; d < H1; ++d) {
            wl2c[d] = Wl2[d * C2 + lane];
            wr2c[d] = Wr2[d * C2 + lane];
        }
        bl2c = bl2[lane]; br2c = br2[lane];
    }

    for (int n = wave; n < BKT; n += 4) {
        int g = bkt * BKT + n;
        if (g >= NN) break;
        int deg = hist[n] + 1;              // + self-loop (edge e==0)
        int nb = nbase[n];

        float4 xrq = ((const float4*)(xr + (size_t)g * D))[q];

        int srcs[RC];
        #pragma unroll
        for (int c = 0; c < RC; ++c) {
            int e = c * EPC + eo;
            srcs[c] = (e > 0 && e < deg) ? sorted[nb + e - 1] : g;
        }
        float4 vv[RC];
        #pragma unroll
        for (int c = 0; c < RC; ++c)
            vv[c] = ((const float4*)(xl + (size_t)srcs[c] * D))[q];

        float sc[RC];
        #pragma unroll
        for (int c = 0; c < RC; ++c) {
            int e = c * EPC + eo;
            float s = 0.f;
            float xv[4] = {vv[c].x, vv[c].y, vv[c].z, vv[c].w};
            #pragma unroll
            for (int j = 0; j < 4; ++j) {
                float w = xv[j] + ((const float*)&xrq)[j];
                w = w > 0.f ? w : NEG * w;
                s = fmaf(attq[j], w, s);
            }
            #pragma unroll
            for (int off = 1; off < LPE; off <<= 1)
                s += __shfl_xor(s, off, 64);
            sc[c] = (e < deg) ? s : -1e30f;
        }
        float m = sc[0];
        #pragma unroll
        for (int c = 1; c < RC; ++c) m = fmaxf(m, sc[c]);
        #pragma unroll
        for (int off = LPE; off < 64; off <<= 1)
            m = fmaxf(m, __shfl_xor(m, off, 64));

        float denom = 0.f;
        float acc[4] = {0.f, 0.f, 0.f, 0.f};
        #pragma unroll
        for (int c = 0; c < RC; ++c) {
            float ex = __expf(sc[c] - m);
            denom += ex;
            float xv[4] = {vv[c].x, vv[c].y, vv[c].z, vv[c].w};
            #pragma unroll
            for (int j = 0; j < 4; ++j) acc[j] = fmaf(ex, xv[j], acc[j]);
        }

        // rare continuation: deg > 64 (online rescale)
        for (int e0 = RC * EPC; e0 < deg; e0 += EPC) {
            int e = e0 + eo;
            int src = (e < deg) ? sorted[nb + e - 1] : g;
            float4 v = ((const float4*)(xl + (size_t)src * D))[q];
            float s = 0.f;
            float xv[4] = {v.x, v.y, v.z, v.w};
            #pragma unroll
            for (int j = 0; j < 4; ++j) {
                float w = xv[j] + ((const float*)&xrq)[j];
                w = w > 0.f ? w : NEG * w;
                s = fmaf(attq[j], w, s);
            }
            #pragma unroll
            for (int off = 1; off < LPE; off <<= 1)
                s += __shfl_xor(s, off, 64);
            if (e >= deg) s = -1e30f;
            float cm = s;
            #pragma unroll
            for (int off = LPE; off < 64; off <<= 1)
                cm = fmaxf(cm, __shfl_xor(cm, off, 64));
            float newm = fmaxf(m, cm);
            float scale = __expf(m - newm);
            float ex = __expf(s - newm);
            denom = denom * scale + ex;
            #pragma unroll
            for (int j = 0; j < 4; ++j)
                acc[j] = fmaf(ex, xv[j], acc[j] * scale);
            m = newm;
        }

        #pragma unroll
        for (int off = LPE; off < 64; off <<= 1) {
            denom += __shfl_xor(denom, off, 64);
            #pragma unroll
            for (int j = 0; j < 4; ++j)
                acc[j] += __shfl_xor(acc[j], off, 64);
        }
        float inv = 1.f / denom;

        if (FUSE_MID) {
            float h[4];
            #pragma unroll
            for (int j = 0; j < 4; ++j)
                h[j] = fmaxf(acc[j] * inv + biasq[j], 0.f);
            float hd[H1];
            #pragma unroll
            for (int d = 0; d < H1; ++d)
                hd[d] = __shfl(h[d & 3], d >> 2, 64);
            if (lane < C2) {
                float al = bl2c, ar = br2c;
                #pragma unroll
                for (int d = 0; d < H1; ++d) {
                    al = fmaf(hd[d], wl2c[d], al);
                    ar = fmaf(hd[d], wr2c[d], ar);
                }
                out [(size_t)g * C2 + lane] = al;
                out2[(size_t)g * C2 + lane] = ar;
            }
        } else {
            if (eo == 0) {
                float4 r;
                r.x = acc[0] * inv + biasq[0];
                r.y = acc[1] * inv + biasq[1];
                r.z = acc[2] * inv + biasq[2];
                r.w = acc[3] * inv + biasq[3];
                ((float4*)(out + (size_t)g * D))[q] = r;
            }
        }
    }
}

extern "C" void kernel_launch(void* const* d_in, const int* in_sizes, int n_in,
                              void* d_out, int out_size, void* d_ws, size_t ws_size,
                              hipStream_t stream) {
    const float* x     = (const float*)d_in[0];
    const int*   ei    = (const int*)d_in[1];
    const float* Wl1   = (const float*)d_in[2];
    const float* bl1   = (const float*)d_in[3];
    const float* Wr1   = (const float*)d_in[4];
    const float* br1   = (const float*)d_in[5];
    const float* att1  = (const float*)d_in[6];
    const float* bias1 = (const float*)d_in[7];
    const float* Wl2   = (const float*)d_in[8];
    const float* bl2   = (const float*)d_in[9];
    const float* Wr2   = (const float*)d_in[10];
    const float* br2   = (const float*)d_in[11];
    const float* att2  = (const float*)d_in[12];
    const float* bias2 = (const float*)d_in[13];
    float* out = (float*)d_out;

    // workspace layout
    int* bedges = (int*)d_ws;                        // NBP*CAP        (16.06 MB)
    int* gcur1  = bedges + (size_t)NBP * CAP;        // 32
    int* gcur2  = gcur1 + SB;                        // NBP
    float* xl1  = (float*)(gcur2 + NBP);             // NN*H1
    float* xr1  = xl1 + (size_t)NN * H1;             // NN*H1
    int* sup1   = (int*)(xr1 + (size_t)NN * H1);     // SB*SCAP        (14.08 MB)
    float* xl2  = (float*)sup1;                      // overlay: sup1 dead after k_p2
    float* xr2  = xl2 + (size_t)NN * C2;             // NN*C2 (fits in sup1 region)

    hipMemsetAsync(gcur1, 0, (SB + NBP) * sizeof(int), stream);

    int gN = (NN + 255) / 256;
    k_lin1<<<gN, 256, 0, stream>>>(x, Wl1, bl1, Wr1, br1, xl1, xr1);
    k_p1<<<256, 512, 0, stream>>>(ei, gcur1, sup1);
    k_p2<<<256, 512, 0, stream>>>(sup1, gcur1, gcur2, bedges);
    k_gat3<H1, true><<<NB, 256, 0, stream>>>(bedges, gcur2, xl1, xr1, att1, bias1,
                                             Wl2, bl2, Wr2, br2, xl2, xr2);
    k_gat3<C2, false><<<NB, 256, 0, stream>>>(bedges, gcur2, xl2, xr2, att2, bias2,
                                              nullptr, nullptr, nullptr, nullptr,
                                              out, nullptr);
}

// Round 6
// 200.068 us; speedup vs baseline: 1.0828x; 1.0828x over previous
//
#include <hip/hip_runtime.h>

#define NN 100000
#define NE 3200000
#define FIN 256
#define H1 8
#define C2 16
#define NEG 0.2f

#define BKT 64                        // dst nodes per fine bucket
#define NB 1563                       // fine buckets with real nodes
#define NBP 1568                      // padded fine buckets (32 supers * 49)
#define CAP 2560                      // max edges per fine bucket (mean 2048)
#define SB 32                         // super-buckets
#define SBN 3136                      // nodes per super (49 * 64)
#define FPS 49                        // fine buckets per super
#define SCAP 110000                   // super region capacity (mean 100000)
#define EPB1 12500                    // NE / 256
#define P2CAP 13760                   // >= ceil(SCAP/8)

// ---- layer-1 linear: xl1 = x@Wl1+bl1, xr1 = x@Wr1+br1 (one thread/node) ----
__global__ __launch_bounds__(256) void k_lin1(
        const float* __restrict__ x,
        const float* __restrict__ Wl, const float* __restrict__ bl,
        const float* __restrict__ Wr, const float* __restrict__ br,
        float* __restrict__ xl1, float* __restrict__ xr1) {
    int n = blockIdx.x * 256 + threadIdx.x;
    if (n >= NN) return;
    float accl[H1], accr[H1];
    #pragma unroll
    for (int h = 0; h < H1; ++h) { accl[h] = bl[h]; accr[h] = br[h]; }
    const float4* xrow = (const float4*)(x + (size_t)n * FIN);
    for (int j = 0; j < FIN / 4; ++j) {
        float4 v = xrow[j];
        float xv[4] = {v.x, v.y, v.z, v.w};
        #pragma unroll
        for (int q = 0; q < 4; ++q) {
            int f = j * 4 + q;
            #pragma unroll
            for (int h = 0; h < H1; ++h) {
                accl[h] = fmaf(xv[q], Wl[f * H1 + h], accl[h]);
                accr[h] = fmaf(xv[q], Wr[f * H1 + h], accr[h]);
            }
        }
    }
    #pragma unroll
    for (int h = 0; h < H1; ++h) {
        xl1[(size_t)n * H1 + h] = accl[h];
        xr1[(size_t)n * H1 + h] = accr[h];
    }
}

// ---- partition stage 1: edges -> 32 super-buckets, LDS sort, coalesced flush
__global__ __launch_bounds__(512) void k_p1(const int* __restrict__ ei,
                                            int* __restrict__ gcur1,
                                            int* __restrict__ sup1) {
    __shared__ int buf[EPB1];
    __shared__ int cnt[SB], nb[SB], cnt2[SB], gb[SB];
    int tid = threadIdx.x;
    int base = blockIdx.x * EPB1;
    if (tid < SB) { cnt[tid] = 0; cnt2[tid] = 0; }
    __syncthreads();
    for (int i = tid; i < EPB1; i += 512)
        atomicAdd(&cnt[ei[NE + base + i] / SBN], 1);
    __syncthreads();
    if (tid < SB) {                       // exclusive scan (one wave) + reserve
        int v = cnt[tid], inc = v;
        #pragma unroll
        for (int off = 1; off < SB; off <<= 1) {
            int u = __shfl_up(inc, off, 64);
            if (tid >= off) inc += u;
        }
        nb[tid] = inc - v;
        gb[tid] = atomicAdd(&gcur1[tid], v);
    }
    __syncthreads();
    for (int i = tid; i < EPB1; i += 512) {
        int src = ei[base + i];
        int dst = ei[NE + base + i];
        int s = dst / SBN;
        int r = dst - s * SBN;
        int k = atomicAdd(&cnt2[s], 1);
        buf[nb[s] + k] = (r << 17) | src;
    }
    __syncthreads();
    for (int s = 0; s < SB; ++s) {        // coalesced run flush
        int c = cnt[s], b = gb[s], o = nb[s];
        size_t dbase = (size_t)s * SCAP + b;
        for (int i = tid; i < c; i += 512)
            if (b + i < SCAP) sup1[dbase + i] = buf[o + i];
    }
}

// ---- partition stage 2: super-bucket slice -> 49 fine buckets ----
__global__ __launch_bounds__(512) void k_p2(const int* __restrict__ sup1,
                                            const int* __restrict__ gcur1,
                                            int* __restrict__ gcur2,
                                            int* __restrict__ bedges) {
    __shared__ int buf[P2CAP];
    __shared__ int cnt[FPS], nb[FPS], cnt2[FPS], gb[FPS];
    int s   = blockIdx.x >> 3;
    int sub = blockIdx.x & 7;
    int tid = threadIdx.x;
    int total = gcur1[s]; if (total > SCAP) total = SCAP;
    int beg = (int)((long)total * sub / 8);
    int end = (int)((long)total * (sub + 1) / 8);
    int n = end - beg;
    const int* sp = sup1 + (size_t)s * SCAP + beg;
    if (tid < FPS) { cnt[tid] = 0; cnt2[tid] = 0; }
    __syncthreads();
    for (int i = tid; i < n; i += 512)
        atomicAdd(&cnt[(sp[i] >> 17) >> 6], 1);
    __syncthreads();
    if (tid < 64) {                       // exclusive scan (one wave) + reserve
        int v = (tid < FPS) ? cnt[tid] : 0, inc = v;
        #pragma unroll
        for (int off = 1; off < 64; off <<= 1) {
            int u = __shfl_up(inc, off, 64);
            if (tid >= off) inc += u;
        }
        if (tid < FPS) {
            nb[tid] = inc - v;
            gb[tid] = atomicAdd(&gcur2[s * FPS + tid], v);
        }
    }
    __syncthreads();
    for (int i = tid; i < n; i += 512) {
        int pk = sp[i];
        int fb = (pk >> 17) >> 6;
        int k = atomicAdd(&cnt2[fb], 1);
        buf[nb[fb] + k] = (((pk >> 17) & 63) << 17) | (pk & 0x1FFFF);
    }
    __syncthreads();
    for (int fb = 0; fb < FPS; ++fb) {    // coalesced run flush
        int c = cnt[fb], b = gb[fb], o = nb[fb];
        size_t dbase = (size_t)(s * FPS + fb) * CAP + b;
        for (int i = tid; i < c; i += 512)
            if (b + i < CAP) bedges[dbase + i] = buf[o + i];
    }
}

// ---- one-shot per-bucket counting sort (in-place into bedges) + meta ----
__global__ __launch_bounds__(256) void k_sort(int* __restrict__ bedges,
                                              const int* __restrict__ gcur2,
                                              int* __restrict__ meta) {
    __shared__ int sorted[CAP];
    __shared__ int hist[BKT], nbase[BKT], scnt[BKT];
    int bkt = blockIdx.x;
    int tid = threadIdx.x;
    int ecnt = gcur2[bkt]; if (ecnt > CAP) ecnt = CAP;
    int* be = bedges + (size_t)bkt * CAP;
    if (tid < BKT) { hist[tid] = 0; scnt[tid] = 0; }
    __syncthreads();
    for (int i = tid; i < ecnt; i += 256)
        atomicAdd(&hist[be[i] >> 17], 1);
    __syncthreads();
    if (tid < BKT) {                       // wave-parallel exclusive scan
        int v = hist[tid], inc = v;
        #pragma unroll
        for (int off = 1; off < 64; off <<= 1) {
            int u = __shfl_up(inc, off, 64);
            if (tid >= off) inc += u;
        }
        nbase[tid] = inc - v;
        meta[bkt * BKT + tid] = ((inc - v) << 16) | v;   // base<<16 | count
    }
    __syncthreads();
    for (int i = tid; i < ecnt; i += 256) {
        int pk = be[i];
        int dl = pk >> 17;
        int r = atomicAdd(&scnt[dl], 1);
        sorted[nbase[dl] + r] = pk & 0x1FFFF;
    }
    __syncthreads();
    for (int i = tid; i < ecnt; i += 256)  // in-place coalesced flush
        be[i] = sorted[i];
}

// ---- GATv2 gather: no LDS, no sort, no max-subtraction, deg-guarded chunks
template<int D, bool FUSE_MID>
__global__ __launch_bounds__(128) void k_gat4(
        const int* __restrict__ sorted_g, const int* __restrict__ meta,
        const float* __restrict__ xl, const float* __restrict__ xr,
        const float* __restrict__ att, const float* __restrict__ bias,
        const float* __restrict__ Wl2, const float* __restrict__ bl2,
        const float* __restrict__ Wr2, const float* __restrict__ br2,
        float* __restrict__ out, float* __restrict__ out2) {
    constexpr int LPE = D / 4;     // lanes per edge
    constexpr int EPC = 64 / LPE;  // edges per chunk
    constexpr int RC  = LPE;       // register chunks covering 64 edges

    int wid  = (blockIdx.x * 128 + threadIdx.x) >> 6;   // global wave id
    int lane = threadIdx.x & 63;
    int q  = lane & (LPE - 1);
    int eo = lane / LPE;

    float attq[4], biasq[4];
    #pragma unroll
    for (int j = 0; j < 4; ++j) { attq[j] = att[q * 4 + j]; biasq[j] = bias[q * 4 + j]; }
    float wl2c[H1], wr2c[H1], bl2c = 0.f, br2c = 0.f;
    if (FUSE_MID && lane < C2) {
        #pragma unroll
        for (int d = 0; d < H1; ++d) {
            wl2c[d] = Wl2[d * C2 + lane];
            wr2c[d] = Wr2[d * C2 + lane];
        }
        bl2c = bl2[lane]; br2c = br2[lane];
    }

    #pragma unroll 1
    for (int i = 0; i < 16; ++i) {
        int g = wid * 16 + i;                 // 3125*32 == NN exactly
        int mt = meta[g];
        int deg = (mt & 0xFFFF) + 1;          // + self-loop (edge e==0)
        const int* sg = sorted_g + (size_t)(g >> 6) * CAP + (mt >> 16);

        float4 xr4 = ((const float4*)(xr + (size_t)g * D))[q];
        float xrq[4] = {xr4.x, xr4.y, xr4.z, xr4.w};

        float denom = 0.f;
        float acc[4] = {0.f, 0.f, 0.f, 0.f};

        #pragma unroll
        for (int c = 0; c < RC; ++c) {
            if (c == 0 || deg > c * EPC) {    // wave-uniform guard
                int e = c * EPC + eo;
                int src = (e > 0 && e < deg) ? sg[e - 1] : g;
                float4 v = ((const float4*)(xl + (size_t)src * D))[q];
                float xv[4] = {v.x, v.y, v.z, v.w};
                float s = 0.f;
                #pragma unroll
                for (int j = 0; j < 4; ++j) {
                    float w = xv[j] + xrq[j];
                    w = fmaxf(w, NEG * w);    // leaky-relu (NEG < 1)
                    s = fmaf(attq[j], w, s);
                }
                #pragma unroll
                for (int off = 1; off < LPE; off <<= 1)
                    s += __shfl_xor(s, off, 64);
                float ex = (e < deg) ? __expf(s) : 0.f;   // logits bounded, no max needed
                denom += ex;
                #pragma unroll
                for (int j = 0; j < 4; ++j)
                    acc[j] = fmaf(ex, xv[j], acc[j]);
            }
        }

        // rare continuation: deg > 64
        for (int e0 = 64; e0 < deg; e0 += EPC) {
            int e = e0 + eo;
            int src = (e < deg) ? sg[e - 1] : g;
            float4 v = ((const float4*)(xl + (size_t)src * D))[q];
            float xv[4] = {v.x, v.y, v.z, v.w};
            float s = 0.f;
            #pragma unroll
            for (int j = 0; j < 4; ++j) {
                float w = xv[j] + xrq[j];
                w = fmaxf(w, NEG * w);
                s = fmaf(attq[j], w, s);
            }
            #pragma unroll
            for (int off = 1; off < LPE; off <<= 1)
                s += __shfl_xor(s, off, 64);
            float ex = (e < deg) ? __expf(s) : 0.f;
            denom += ex;
            #pragma unroll
            for (int j = 0; j < 4; ++j)
                acc[j] = fmaf(ex, xv[j], acc[j]);
        }

        // cross-edge butterfly (strides LPE..32)
        #pragma unroll
        for (int off = LPE; off < 64; off <<= 1) {
            denom += __shfl_xor(denom, off, 64);
            #pragma unroll
            for (int j = 0; j < 4; ++j)
                acc[j] += __shfl_xor(acc[j], off, 64);
        }
        float inv = 1.f / denom;

        if (FUSE_MID) {
            float h[4];
            #pragma unroll
            for (int j = 0; j < 4; ++j)
                h[j] = fmaxf(acc[j] * inv + biasq[j], 0.f);
            float hd[H1];
            #pragma unroll
            for (int d = 0; d < H1; ++d)
                hd[d] = __shfl(h[d & 3], d >> 2, 64);
            if (lane < C2) {
                float al = bl2c, ar = br2c;
                #pragma unroll
                for (int d = 0; d < H1; ++d) {
                    al = fmaf(hd[d], wl2c[d], al);
                    ar = fmaf(hd[d], wr2c[d], ar);
                }
                out [(size_t)g * C2 + lane] = al;
                out2[(size_t)g * C2 + lane] = ar;
            }
        } else {
            if (eo == 0) {
                float4 r;
                r.x = acc[0] * inv + biasq[0];
                r.y = acc[1] * inv + biasq[1];
                r.z = acc[2] * inv + biasq[2];
                r.w = acc[3] * inv + biasq[3];
                ((float4*)(out + (size_t)g * D))[q] = r;
            }
        }
    }
}

extern "C" void kernel_launch(void* const* d_in, const int* in_sizes, int n_in,
                              void* d_out, int out_size, void* d_ws, size_t ws_size,
                              hipStream_t stream) {
    const float* x     = (const float*)d_in[0];
    const int*   ei    = (const int*)d_in[1];
    const float* Wl1   = (const float*)d_in[2];
    const float* bl1   = (const float*)d_in[3];
    const float* Wr1   = (const float*)d_in[4];
    const float* br1   = (const float*)d_in[5];
    const float* att1  = (const float*)d_in[6];
    const float* bias1 = (const float*)d_in[7];
    const float* Wl2   = (const float*)d_in[8];
    const float* bl2   = (const float*)d_in[9];
    const float* Wr2   = (const float*)d_in[10];
    const float* br2   = (const float*)d_in[11];
    const float* att2  = (const float*)d_in[12];
    const float* bias2 = (const float*)d_in[13];
    float* out = (float*)d_out;

    // workspace layout
    int* bedges = (int*)d_ws;                        // NBP*CAP (sorted in-place)
    int* gcur1  = bedges + (size_t)NBP * CAP;        // 32
    int* gcur2  = gcur1 + SB;                        // NBP
    int* meta   = gcur2 + NBP;                       // NBP*64
    float* xl1  = (float*)(meta + NBP * BKT);        // NN*H1
    float* xr1  = xl1 + (size_t)NN * H1;             // NN*H1
    int* sup1   = (int*)(xr1 + (size_t)NN * H1);     // SB*SCAP (14.08 MB)
    float* xl2  = (float*)sup1;                      // overlay: sup1 dead after k_p2
    float* xr2  = xl2 + (size_t)NN * C2;             // NN*C2

    hipMemsetAsync(gcur1, 0, (SB + NBP) * sizeof(int), stream);

    int gN = (NN + 255) / 256;
    k_lin1<<<gN, 256, 0, stream>>>(x, Wl1, bl1, Wr1, br1, xl1, xr1);
    k_p1<<<256, 512, 0, stream>>>(ei, gcur1, sup1);
    k_p2<<<256, 512, 0, stream>>>(sup1, gcur1, gcur2, bedges);
    k_sort<<<NB, 256, 0, stream>>>(bedges, gcur2, meta);
    k_gat4<H1, true><<<3125, 128, 0, stream>>>(bedges, meta, xl1, xr1, att1, bias1,
                                               Wl2, bl2, Wr2, br2, xl2, xr2);
    k_gat4<C2, false><<<3125, 128, 0, stream>>>(bedges, meta, xl2, xr2, att2, bias2,
                                                nullptr, nullptr, nullptr, nullptr,
                                                out, nullptr);
}

// Round 7
// 190.535 us; speedup vs baseline: 1.1370x; 1.0500x over previous
//
#include <hip/hip_runtime.h>

#define NN 100000
#define NE 3200000
#define FIN 256
#define H1 8
#define C2 16
#define NEG 0.2f

#define BKT 64                        // dst nodes per fine bucket
#define NB 1563                       // fine buckets with real nodes
#define NBP 1568                      // padded fine buckets (32 supers * 49)
#define CAP 2560                      // max edges per fine bucket (mean 2048)
#define SB 32                         // super-buckets
#define SBN 3136                      // nodes per super (49 * 64)
#define FPS 49                        // fine buckets per super
#define SCAP 110000                   // super region capacity (mean 100352)
#define EPB1 3125                     // NE / 1024
#define P2CAP 3520                    // >= max super total / 32

// ---- layer-1 linear: lane = node, wave = K-quarter, weights via s_load ----
__global__ __launch_bounds__(256) void k_lin1(
        const float* __restrict__ x,
        const float* __restrict__ Wl, const float* __restrict__ bl,
        const float* __restrict__ Wr, const float* __restrict__ br,
        float* __restrict__ xl1, float* __restrict__ xr1) {
    __shared__ float part[4][64][20];          // [wave][node][16 vals], pad 20
    int lane = threadIdx.x & 63;
    int w    = __builtin_amdgcn_readfirstlane(threadIdx.x >> 6);  // K-quarter
    int n    = blockIdx.x * 64 + lane;
    int nc   = n < NN ? n : NN - 1;            // clamp (writes guarded later)

    const float4* xrow4 = (const float4*)(x + (size_t)nc * FIN) + w * 16;
    float accl[8] = {0,0,0,0,0,0,0,0}, accr[8] = {0,0,0,0,0,0,0,0};
    #pragma unroll
    for (int i = 0; i < 16; ++i) {
        float4 v = xrow4[i];
        int fbase = (w * 64 + i * 4) * 8;      // uniform -> s_load weights
        #pragma unroll
        for (int q = 0; q < 4; ++q) {
            float xv = q == 0 ? v.x : q == 1 ? v.y : q == 2 ? v.z : v.w;
            #pragma unroll
            for (int h = 0; h < 8; ++h) {
                accl[h] = fmaf(xv, Wl[fbase + q * 8 + h], accl[h]);
                accr[h] = fmaf(xv, Wr[fbase + q * 8 + h], accr[h]);
            }
        }
    }
    #pragma unroll
    for (int h = 0; h < 8; ++h) {
        part[w][lane][h]     = accl[h];
        part[w][lane][8 + h] = accr[h];
    }
    __syncthreads();

    // reduce 4 K-quarters; thread t -> node t>>2, 4-float segment t&3
    int n2 = threadIdx.x >> 2, seg = threadIdx.x & 3;
    float4 a = *(const float4*)&part[0][n2][seg * 4];
    float4 b = *(const float4*)&part[1][n2][seg * 4];
    float4 c = *(const float4*)&part[2][n2][seg * 4];
    float4 d = *(const float4*)&part[3][n2][seg * 4];
    float4 s;
    s.x = a.x + b.x + c.x + d.x;
    s.y = a.y + b.y + c.y + d.y;
    s.z = a.z + b.z + c.z + d.z;
    s.w = a.w + b.w + c.w + d.w;
    int gn = blockIdx.x * 64 + n2;
    if (gn < NN) {
        if (seg < 2) {
            float4 bv = ((const float4*)bl)[seg];
            s.x += bv.x; s.y += bv.y; s.z += bv.z; s.w += bv.w;
            ((float4*)(xl1 + (size_t)gn * H1))[seg] = s;
        } else {
            float4 bv = ((const float4*)br)[seg - 2];
            s.x += bv.x; s.y += bv.y; s.z += bv.z; s.w += bv.w;
            ((float4*)(xr1 + (size_t)gn * H1))[seg - 2] = s;
        }
    }
}

// ---- partition stage 1: edges -> 32 super-buckets (register-cached edges) --
__global__ __launch_bounds__(512) void k_p1(const int* __restrict__ ei,
                                            int* __restrict__ gcur1,
                                            int* __restrict__ sup1) {
    __shared__ int buf[EPB1];                  // 12.5 KB
    __shared__ int cnt[SB], nb[SB], cnt2[SB], gb[SB];
    int tid = threadIdx.x;
    int base = blockIdx.x * EPB1;
    if (tid < SB) { cnt[tid] = 0; cnt2[tid] = 0; }
    int es[7], ed[7];
    #pragma unroll
    for (int r = 0; r < 7; ++r) {
        int i = tid + r * 512;
        if (i < EPB1) { es[r] = ei[base + i]; ed[r] = ei[NE + base + i]; }
    }
    __syncthreads();
    #pragma unroll
    for (int r = 0; r < 7; ++r) {
        int i = tid + r * 512;
        if (i < EPB1) atomicAdd(&cnt[ed[r] / SBN], 1);
    }
    __syncthreads();
    if (tid < SB) {                            // scan + global reserve
        int v = cnt[tid], inc = v;
        #pragma unroll
        for (int off = 1; off < SB; off <<= 1) {
            int u = __shfl_up(inc, off, 64);
            if (tid >= off) inc += u;
        }
        nb[tid] = inc - v;
        gb[tid] = atomicAdd(&gcur1[tid], v);
    }
    __syncthreads();
    #pragma unroll
    for (int r = 0; r < 7; ++r) {
        int i = tid + r * 512;
        if (i < EPB1) {
            int s = ed[r] / SBN;
            int rr = ed[r] - s * SBN;
            int k = atomicAdd(&cnt2[s], 1);
            buf[nb[s] + k] = (rr << 17) | es[r];
        }
    }
    __syncthreads();
    for (int s = 0; s < SB; ++s) {             // coalesced run flush
        int c = cnt[s], b = gb[s], o = nb[s];
        size_t dbase = (size_t)s * SCAP + b;
        for (int i = tid; i < c; i += 512)
            if (b + i < SCAP) sup1[dbase + i] = buf[o + i];
    }
}

// ---- partition stage 2: super slice -> 49 fine buckets (32 slices/super) ---
__global__ __launch_bounds__(512) void k_p2(const int* __restrict__ sup1,
                                            const int* __restrict__ gcur1,
                                            int* __restrict__ gcur2,
                                            int* __restrict__ bedges) {
    __shared__ int buf[P2CAP];                 // 14 KB
    __shared__ int cnt[FPS], nb[FPS], cnt2[FPS], gb[FPS];
    int s   = blockIdx.x >> 5;
    int sub = blockIdx.x & 31;
    int tid = threadIdx.x;
    int total = gcur1[s]; if (total > SCAP) total = SCAP;
    int beg = (int)((long)total * sub / 32);
    int end = (int)((long)total * (sub + 1) / 32);
    int n = end - beg;
    const int* sp = sup1 + (size_t)s * SCAP + beg;
    if (tid < FPS) { cnt[tid] = 0; cnt2[tid] = 0; }
    int pk[7];
    #pragma unroll
    for (int r = 0; r < 7; ++r) {
        int i = tid + r * 512;
        if (i < n) pk[r] = sp[i];
    }
    __syncthreads();
    #pragma unroll
    for (int r = 0; r < 7; ++r) {
        int i = tid + r * 512;
        if (i < n) atomicAdd(&cnt[(pk[r] >> 17) >> 6], 1);
    }
    __syncthreads();
    if (tid < 64) {
        int v = (tid < FPS) ? cnt[tid] : 0, inc = v;
        #pragma unroll
        for (int off = 1; off < 64; off <<= 1) {
            int u = __shfl_up(inc, off, 64);
            if (tid >= off) inc += u;
        }
        if (tid < FPS) {
            nb[tid] = inc - v;
            gb[tid] = atomicAdd(&gcur2[s * FPS + tid], v);
        }
    }
    __syncthreads();
    #pragma unroll
    for (int r = 0; r < 7; ++r) {
        int i = tid + r * 512;
        if (i < n) {
            int fb = (pk[r] >> 17) >> 6;
            int k = atomicAdd(&cnt2[fb], 1);
            buf[nb[fb] + k] = (((pk[r] >> 17) & 63) << 17) | (pk[r] & 0x1FFFF);
        }
    }
    __syncthreads();
    for (int fb = 0; fb < FPS; ++fb) {         // coalesced run flush
        int c = cnt[fb], b = gb[fb], o = nb[fb];
        size_t dbase = (size_t)(s * FPS + fb) * CAP + b;
        for (int i = tid; i < c; i += 512)
            if (b + i < CAP) bedges[dbase + i] = buf[o + i];
    }
}

// ---- one-shot per-bucket counting sort (in-place into bedges) + meta ----
__global__ __launch_bounds__(256) void k_sort(int* __restrict__ bedges,
                                              const int* __restrict__ gcur2,
                                              int* __restrict__ meta) {
    __shared__ int sorted[CAP];
    __shared__ int hist[BKT], nbase[BKT], scnt[BKT];
    int bkt = blockIdx.x;
    int tid = threadIdx.x;
    int ecnt = gcur2[bkt]; if (ecnt > CAP) ecnt = CAP;
    int* be = bedges + (size_t)bkt * CAP;
    if (tid < BKT) { hist[tid] = 0; scnt[tid] = 0; }
    __syncthreads();
    for (int i = tid; i < ecnt; i += 256)
        atomicAdd(&hist[be[i] >> 17], 1);
    __syncthreads();
    if (tid < BKT) {
        int v = hist[tid], inc = v;
        #pragma unroll
        for (int off = 1; off < 64; off <<= 1) {
            int u = __shfl_up(inc, off, 64);
            if (tid >= off) inc += u;
        }
        nbase[tid] = inc - v;
        meta[bkt * BKT + tid] = ((inc - v) << 16) | v;   // base<<16 | count
    }
    __syncthreads();
    for (int i = tid; i < ecnt; i += 256) {
        int pk = be[i];
        int dl = pk >> 17;
        int r = atomicAdd(&scnt[dl], 1);
        sorted[nbase[dl] + r] = pk & 0x1FFFF;
    }
    __syncthreads();
    for (int i = tid; i < ecnt; i += 256)
        be[i] = sorted[i];
}

// ---- GATv2 gather: no LDS, no max-subtraction, deg-guarded chunks ----
template<int D, bool FUSE_MID>
__global__ __launch_bounds__(128) void k_gat4(
        const int* __restrict__ sorted_g, const int* __restrict__ meta,
        const float* __restrict__ xl, const float* __restrict__ xr,
        const float* __restrict__ att, const float* __restrict__ bias,
        const float* __restrict__ Wl2, const float* __restrict__ bl2,
        const float* __restrict__ Wr2, const float* __restrict__ br2,
        float* __restrict__ out, float* __restrict__ out2) {
    constexpr int LPE = D / 4;
    constexpr int EPC = 64 / LPE;
    constexpr int RC  = LPE;

    int wid  = (blockIdx.x * 128 + threadIdx.x) >> 6;
    int lane = threadIdx.x & 63;
    int q  = lane & (LPE - 1);
    int eo = lane / LPE;

    float attq[4], biasq[4];
    #pragma unroll
    for (int j = 0; j < 4; ++j) { attq[j] = att[q * 4 + j]; biasq[j] = bias[q * 4 + j]; }
    float wl2c[H1], wr2c[H1], bl2c = 0.f, br2c = 0.f;
    if (FUSE_MID && lane < C2) {
        #pragma unroll
        for (int d = 0; d < H1; ++d) {
            wl2c[d] = Wl2[d * C2 + lane];
            wr2c[d] = Wr2[d * C2 + lane];
        }
        bl2c = bl2[lane]; br2c = br2[lane];
    }

    #pragma unroll 1
    for (int i = 0; i < 16; ++i) {
        int g = wid * 16 + i;                 // 3125*32 == NN exactly
        int mt = meta[g];
        int deg = (mt & 0xFFFF) + 1;          // + self-loop (edge e==0)
        const int* sg = sorted_g + (size_t)(g >> 6) * CAP + (mt >> 16);

        float4 xr4 = ((const float4*)(xr + (size_t)g * D))[q];
        float xrq[4] = {xr4.x, xr4.y, xr4.z, xr4.w};

        float denom = 0.f;
        float acc[4] = {0.f, 0.f, 0.f, 0.f};

        #pragma unroll
        for (int c = 0; c < RC; ++c) {
            if (c == 0 || deg > c * EPC) {    // wave-uniform guard
                int e = c * EPC + eo;
                int src = (e > 0 && e < deg) ? sg[e - 1] : g;
                float4 v = ((const float4*)(xl + (size_t)src * D))[q];
                float xv[4] = {v.x, v.y, v.z, v.w};
                float s = 0.f;
                #pragma unroll
                for (int j = 0; j < 4; ++j) {
                    float w = xv[j] + xrq[j];
                    w = fmaxf(w, NEG * w);    // leaky-relu
                    s = fmaf(attq[j], w, s);
                }
                #pragma unroll
                for (int off = 1; off < LPE; off <<= 1)
                    s += __shfl_xor(s, off, 64);
                float ex = (e < deg) ? __expf(s) : 0.f;
                denom += ex;
                #pragma unroll
                for (int j = 0; j < 4; ++j)
                    acc[j] = fmaf(ex, xv[j], acc[j]);
            }
        }

        for (int e0 = 64; e0 < deg; e0 += EPC) {   // rare: deg > 64
            int e = e0 + eo;
            int src = (e < deg) ? sg[e - 1] : g;
            float4 v = ((const float4*)(xl + (size_t)src * D))[q];
            float xv[4] = {v.x, v.y, v.z, v.w};
            float s = 0.f;
            #pragma unroll
            for (int j = 0; j < 4; ++j) {
                float w = xv[j] + xrq[j];
                w = fmaxf(w, NEG * w);
                s = fmaf(attq[j], w, s);
            }
            #pragma unroll
            for (int off = 1; off < LPE; off <<= 1)
                s += __shfl_xor(s, off, 64);
            float ex = (e < deg) ? __expf(s) : 0.f;
            denom += ex;
            #pragma unroll
            for (int j = 0; j < 4; ++j)
                acc[j] = fmaf(ex, xv[j], acc[j]);
        }

        #pragma unroll
        for (int off = LPE; off < 64; off <<= 1) {
            denom += __shfl_xor(denom, off, 64);
            #pragma unroll
            for (int j = 0; j < 4; ++j)
                acc[j] += __shfl_xor(acc[j], off, 64);
        }
        float inv = 1.f / denom;

        if (FUSE_MID) {
            float h[4];
            #pragma unroll
            for (int j = 0; j < 4; ++j)
                h[j] = fmaxf(acc[j] * inv + biasq[j], 0.f);
            float hd[H1];
            #pragma unroll
            for (int d = 0; d < H1; ++d)
                hd[d] = __shfl(h[d & 3], d >> 2, 64);
            if (lane < C2) {
                float al = bl2c, ar = br2c;
                #pragma unroll
                for (int d = 0; d < H1; ++d) {
                    al = fmaf(hd[d], wl2c[d], al);
                    ar = fmaf(hd[d], wr2c[d], ar);
                }
                out [(size_t)g * C2 + lane] = al;
                out2[(size_t)g * C2 + lane] = ar;
            }
        } else {
            if (eo == 0) {
                float4 r;
                r.x = acc[0] * inv + biasq[0];
                r.y = acc[1] * inv + biasq[1];
                r.z = acc[2] * inv + biasq[2];
                r.w = acc[3] * inv + biasq[3];
                ((float4*)(out + (size_t)g * D))[q] = r;
            }
        }
    }
}

extern "C" void kernel_launch(void* const* d_in, const int* in_sizes, int n_in,
                              void* d_out, int out_size, void* d_ws, size_t ws_size,
                              hipStream_t stream) {
    const float* x     = (const float*)d_in[0];
    const int*   ei    = (const int*)d_in[1];
    const float* Wl1   = (const float*)d_in[2];
    const float* bl1   = (const float*)d_in[3];
    const float* Wr1   = (const float*)d_in[4];
    const float* br1   = (const float*)d_in[5];
    const float* att1  = (const float*)d_in[6];
    const float* bias1 = (const float*)d_in[7];
    const float* Wl2   = (const float*)d_in[8];
    const float* bl2   = (const float*)d_in[9];
    const float* Wr2   = (const float*)d_in[10];
    const float* br2   = (const float*)d_in[11];
    const float* att2  = (const float*)d_in[12];
    const float* bias2 = (const float*)d_in[13];
    float* out = (float*)d_out;

    // workspace layout
    int* bedges = (int*)d_ws;                        // NBP*CAP (sorted in-place)
    int* gcur1  = bedges + (size_t)NBP * CAP;        // 32
    int* gcur2  = gcur1 + SB;                        // NBP
    int* meta   = gcur2 + NBP;                       // NBP*64
    float* xl1  = (float*)(meta + NBP * BKT);        // NN*H1
    float* xr1  = xl1 + (size_t)NN * H1;             // NN*H1
    int* sup1   = (int*)(xr1 + (size_t)NN * H1);     // SB*SCAP (14.08 MB)
    float* xl2  = (float*)sup1;                      // overlay: sup1 dead after k_p2
    float* xr2  = xl2 + (size_t)NN * C2;             // NN*C2

    hipMemsetAsync(gcur1, 0, (SB + NBP) * sizeof(int), stream);

    k_lin1<<<1563, 256, 0, stream>>>(x, Wl1, bl1, Wr1, br1, xl1, xr1);
    k_p1<<<1024, 512, 0, stream>>>(ei, gcur1, sup1);
    k_p2<<<1024, 512, 0, stream>>>(sup1, gcur1, gcur2, bedges);
    k_sort<<<NB, 256, 0, stream>>>(bedges, gcur2, meta);
    k_gat4<H1, true><<<3125, 128, 0, stream>>>(bedges, meta, xl1, xr1, att1, bias1,
                                               Wl2, bl2, Wr2, br2, xl2, xr2);
    k_gat4<C2, false><<<3125, 128, 0, stream>>>(bedges, meta, xl2, xr2, att2, bias2,
                                                nullptr, nullptr, nullptr, nullptr,
                                                out, nullptr);
}

// Round 8
// 170.442 us; speedup vs baseline: 1.2710x; 1.1179x over previous
//
#include <hip/hip_runtime.h>

#define NN 100000
#define NE 3200000
#define FIN 256
#define H1 8
#define C2 16
#define NEG 0.2f

#define BKT 64                        // dst nodes per fine bucket
#define NB 1563                       // fine buckets with real nodes
#define NBP 1568                      // padded fine buckets (32 supers * 49)
#define CAP 2560                      // max edges per fine bucket (mean 2048)
#define SB 32                         // super-buckets
#define SBN 3136                      // nodes per super (49 * 64)
#define FPS 49                        // fine buckets per super
#define SCAP 110000                   // super region capacity (mean 100352)
#define P1B 1024                      // partition-1 blocks
#define EPB1 3125                     // NE / P1B
#define LINB 782                      // lin1 blocks (128 nodes each)
#define P2CAP 3520                    // >= max super slice

// ---- fused: blockIdx < P1B -> edge partition stage 1; else layer-1 linear --
__global__ __launch_bounds__(512) void k_a(
        const float* __restrict__ x,
        const float* __restrict__ Wl, const float* __restrict__ bl,
        const float* __restrict__ Wr, const float* __restrict__ br,
        float* __restrict__ xl1, float* __restrict__ xr1,
        const int* __restrict__ ei,
        int* __restrict__ gcur1, int* __restrict__ sup1) {
    __shared__ int smem[10240];        // 40 KB, shared by both roles
    int tid = threadIdx.x;

    if (blockIdx.x < P1B) {
        // ---------------- partition stage 1 ----------------
        int* buf  = smem;              // EPB1
        int* cnt  = smem + EPB1;
        int* nb   = cnt + SB;
        int* cnt2 = nb + SB;
        int* gb   = cnt2 + SB;
        int base = blockIdx.x * EPB1;
        if (tid < SB) { cnt[tid] = 0; cnt2[tid] = 0; }
        int es[7], ed[7];
        #pragma unroll
        for (int r = 0; r < 7; ++r) {
            int i = tid + r * 512;
            if (i < EPB1) { es[r] = ei[base + i]; ed[r] = ei[NE + base + i]; }
        }
        __syncthreads();
        #pragma unroll
        for (int r = 0; r < 7; ++r) {
            int i = tid + r * 512;
            if (i < EPB1) atomicAdd(&cnt[ed[r] / SBN], 1);
        }
        __syncthreads();
        if (tid < SB) {                // scan + global reserve
            int v = cnt[tid], inc = v;
            #pragma unroll
            for (int off = 1; off < SB; off <<= 1) {
                int u = __shfl_up(inc, off, 64);
                if (tid >= off) inc += u;
            }
            nb[tid] = inc - v;
            gb[tid] = atomicAdd(&gcur1[tid], v);
        }
        __syncthreads();
        #pragma unroll
        for (int r = 0; r < 7; ++r) {
            int i = tid + r * 512;
            if (i < EPB1) {
                int s = ed[r] / SBN;
                int rr = ed[r] - s * SBN;
                int k = atomicAdd(&cnt2[s], 1);
                buf[nb[s] + k] = (rr << 17) | es[r];
            }
        }
        __syncthreads();
        for (int s = 0; s < SB; ++s) { // coalesced run flush
            int c = cnt[s], b = gb[s], o = nb[s];
            size_t dbase = (size_t)s * SCAP + b;
            for (int i = tid; i < c; i += 512)
                if (b + i < SCAP) sup1[dbase + i] = buf[o + i];
        }
    } else {
        // ---------------- layer-1 linear (128 nodes/block) ----------------
        float* part = (float*)smem;    // [8][64][20]
        int lane = tid & 63;
        int w    = __builtin_amdgcn_readfirstlane(tid >> 6);  // 0..7
        int kq   = w & 3;              // K-quarter
        int ng   = w >> 2;             // node group (0/1)
        int blk  = blockIdx.x - P1B;
        int n    = blk * 128 + ng * 64 + lane;
        int nc   = n < NN ? n : NN - 1;

        const float4* xrow4 = (const float4*)(x + (size_t)nc * FIN) + kq * 16;
        float accl[8] = {0,0,0,0,0,0,0,0}, accr[8] = {0,0,0,0,0,0,0,0};
        #pragma unroll
        for (int i = 0; i < 16; ++i) {
            float4 v = xrow4[i];
            int fbase = (kq * 64 + i * 4) * 8;   // uniform -> s_load weights
            #pragma unroll
            for (int q = 0; q < 4; ++q) {
                float xv = q == 0 ? v.x : q == 1 ? v.y : q == 2 ? v.z : v.w;
                #pragma unroll
                for (int h = 0; h < 8; ++h) {
                    accl[h] = fmaf(xv, Wl[fbase + q * 8 + h], accl[h]);
                    accr[h] = fmaf(xv, Wr[fbase + q * 8 + h], accr[h]);
                }
            }
        }
        float* pr = &part[((w) * 64 + lane) * 20];
        #pragma unroll
        for (int h = 0; h < 8; ++h) { pr[h] = accl[h]; pr[8 + h] = accr[h]; }
        __syncthreads();

        // reduce 4 K-quarters; thread t -> node t>>2, float4 segment t&3
        int n2 = tid >> 2, seg = tid & 3;        // n2: 0..127
        int grp = n2 >> 6, l2 = n2 & 63;
        float4 a = *(const float4*)&part[((grp * 4 + 0) * 64 + l2) * 20 + seg * 4];
        float4 b = *(const float4*)&part[((grp * 4 + 1) * 64 + l2) * 20 + seg * 4];
        float4 c = *(const float4*)&part[((grp * 4 + 2) * 64 + l2) * 20 + seg * 4];
        float4 d = *(const float4*)&part[((grp * 4 + 3) * 64 + l2) * 20 + seg * 4];
        float4 s;
        s.x = a.x + b.x + c.x + d.x;
        s.y = a.y + b.y + c.y + d.y;
        s.z = a.z + b.z + c.z + d.z;
        s.w = a.w + b.w + c.w + d.w;
        int gn = blk * 128 + n2;
        if (gn < NN) {
            if (seg < 2) {
                float4 bv = ((const float4*)bl)[seg];
                s.x += bv.x; s.y += bv.y; s.z += bv.z; s.w += bv.w;
                ((float4*)(xl1 + (size_t)gn * H1))[seg] = s;
            } else {
                float4 bv = ((const float4*)br)[seg - 2];
                s.x += bv.x; s.y += bv.y; s.z += bv.z; s.w += bv.w;
                ((float4*)(xr1 + (size_t)gn * H1))[seg - 2] = s;
            }
        }
    }
}

// ---- partition stage 2: super slice -> 49 fine buckets (32 slices/super) ---
__global__ __launch_bounds__(512) void k_p2(const int* __restrict__ sup1,
                                            const int* __restrict__ gcur1,
                                            int* __restrict__ gcur2,
                                            int* __restrict__ bedges) {
    __shared__ int buf[P2CAP];
    __shared__ int cnt[FPS], nb[FPS], cnt2[FPS], gb[FPS];
    int s   = blockIdx.x >> 5;
    int sub = blockIdx.x & 31;
    int tid = threadIdx.x;
    int total = gcur1[s]; if (total > SCAP) total = SCAP;
    int beg = (int)((long)total * sub / 32);
    int end = (int)((long)total * (sub + 1) / 32);
    int n = end - beg;
    const int* sp = sup1 + (size_t)s * SCAP + beg;
    if (tid < FPS) { cnt[tid] = 0; cnt2[tid] = 0; }
    int pk[7];
    #pragma unroll
    for (int r = 0; r < 7; ++r) {
        int i = tid + r * 512;
        if (i < n) pk[r] = sp[i];
    }
    __syncthreads();
    #pragma unroll
    for (int r = 0; r < 7; ++r) {
        int i = tid + r * 512;
        if (i < n) atomicAdd(&cnt[(pk[r] >> 17) >> 6], 1);
    }
    __syncthreads();
    if (tid < 64) {
        int v = (tid < FPS) ? cnt[tid] : 0, inc = v;
        #pragma unroll
        for (int off = 1; off < 64; off <<= 1) {
            int u = __shfl_up(inc, off, 64);
            if (tid >= off) inc += u;
        }
        if (tid < FPS) {
            nb[tid] = inc - v;
            gb[tid] = atomicAdd(&gcur2[s * FPS + tid], v);
        }
    }
    __syncthreads();
    #pragma unroll
    for (int r = 0; r < 7; ++r) {
        int i = tid + r * 512;
        if (i < n) {
            int fb = (pk[r] >> 17) >> 6;
            int k = atomicAdd(&cnt2[fb], 1);
            buf[nb[fb] + k] = (((pk[r] >> 17) & 63) << 17) | (pk[r] & 0x1FFFF);
        }
    }
    __syncthreads();
    for (int fb = 0; fb < FPS; ++fb) {
        int c = cnt[fb], b = gb[fb], o = nb[fb];
        size_t dbase = (size_t)(s * FPS + fb) * CAP + b;
        for (int i = tid; i < c; i += 512)
            if (b + i < CAP) bedges[dbase + i] = buf[o + i];
    }
}

// ---- fused: per-bucket counting sort + layer-1 GAT + mid GEMM ----
__global__ __launch_bounds__(256) void k_sortgat1(
        int* __restrict__ bedges, const int* __restrict__ gcur2,
        int* __restrict__ meta,
        const float* __restrict__ xl, const float* __restrict__ xr,
        const float* __restrict__ att, const float* __restrict__ bias,
        const float* __restrict__ Wl2, const float* __restrict__ bl2,
        const float* __restrict__ Wr2, const float* __restrict__ br2,
        float* __restrict__ xl2, float* __restrict__ xr2) {
    __shared__ int sorted[CAP];
    __shared__ int hist[BKT], nbase[BKT], scnt[BKT];
    int bkt = blockIdx.x;
    int tid = threadIdx.x;
    int ecnt = gcur2[bkt]; if (ecnt > CAP) ecnt = CAP;
    int* be = bedges + (size_t)bkt * CAP;
    if (tid < BKT) { hist[tid] = 0; scnt[tid] = 0; }
    __syncthreads();
    for (int i = tid; i < ecnt; i += 256)
        atomicAdd(&hist[be[i] >> 17], 1);
    __syncthreads();
    if (tid < BKT) {                   // wave-parallel exclusive scan
        int v = hist[tid], inc = v;
        #pragma unroll
        for (int off = 1; off < 64; off <<= 1) {
            int u = __shfl_up(inc, off, 64);
            if (tid >= off) inc += u;
        }
        nbase[tid] = inc - v;
        meta[bkt * BKT + tid] = ((inc - v) << 16) | v;   // for layer 2
    }
    __syncthreads();
    for (int i = tid; i < ecnt; i += 256) {
        int pk = be[i];
        int dl = pk >> 17;
        int r = atomicAdd(&scnt[dl], 1);
        sorted[nbase[dl] + r] = pk & 0x1FFFF;
    }
    __syncthreads();
    for (int i = tid; i < ecnt; i += 256)   // writeback for layer 2
        be[i] = sorted[i];

    // ---------------- layer-1 GAT (D=8) + mid GEMM ----------------
    int wave = tid >> 6, lane = tid & 63;
    int q = lane & 1, eo = lane >> 1;       // LPE=2, EPC=32

    float attq[4], biasq[4];
    #pragma unroll
    for (int j = 0; j < 4; ++j) { attq[j] = att[q * 4 + j]; biasq[j] = bias[q * 4 + j]; }
    float wl2c[H1], wr2c[H1], bl2c = 0.f, br2c = 0.f;
    if (lane < C2) {
        #pragma unroll
        for (int d = 0; d < H1; ++d) {
            wl2c[d] = Wl2[d * C2 + lane];
            wr2c[d] = Wr2[d * C2 + lane];
        }
        bl2c = bl2[lane]; br2c = br2[lane];
    }

    for (int n = wave; n < BKT; n += 4) {
        int g = bkt * BKT + n;
        if (g >= NN) break;
        int deg = hist[n] + 1;              // + self-loop (e==0)
        int nb_ = nbase[n];

        float4 xr4 = ((const float4*)(xr + (size_t)g * H1))[q];
        float xrq[4] = {xr4.x, xr4.y, xr4.z, xr4.w};

        float denom = 0.f;
        float acc[4] = {0.f, 0.f, 0.f, 0.f};

        #pragma unroll
        for (int c = 0; c < 2; ++c) {
            if (c == 0 || deg > 32) {
                int e = c * 32 + eo;
                int src = (e > 0 && e < deg) ? sorted[nb_ + e - 1] : g;
                float4 v = ((const float4*)(xl + (size_t)src * H1))[q];
                float xv[4] = {v.x, v.y, v.z, v.w};
                float s = 0.f;
                #pragma unroll
                for (int j = 0; j < 4; ++j) {
                    float w = xv[j] + xrq[j];
                    w = fmaxf(w, NEG * w);
                    s = fmaf(attq[j], w, s);
                }
                s += __shfl_xor(s, 1, 64);
                float ex = (e < deg) ? __expf(s) : 0.f;
                denom += ex;
                #pragma unroll
                for (int j = 0; j < 4; ++j)
                    acc[j] = fmaf(ex, xv[j], acc[j]);
            }
        }
        for (int e0 = 64; e0 < deg; e0 += 32) {   // rare: deg > 64
            int e = e0 + eo;
            int src = (e < deg) ? sorted[nb_ + e - 1] : g;
            float4 v = ((const float4*)(xl + (size_t)src * H1))[q];
            float xv[4] = {v.x, v.y, v.z, v.w};
            float s = 0.f;
            #pragma unroll
            for (int j = 0; j < 4; ++j) {
                float w = xv[j] + xrq[j];
                w = fmaxf(w, NEG * w);
                s = fmaf(attq[j], w, s);
            }
            s += __shfl_xor(s, 1, 64);
            float ex = (e < deg) ? __expf(s) : 0.f;
            denom += ex;
            #pragma unroll
            for (int j = 0; j < 4; ++j)
                acc[j] = fmaf(ex, xv[j], acc[j]);
        }

        #pragma unroll
        for (int off = 2; off < 64; off <<= 1) {
            denom += __shfl_xor(denom, off, 64);
            #pragma unroll
            for (int j = 0; j < 4; ++j)
                acc[j] += __shfl_xor(acc[j], off, 64);
        }
        float inv = 1.f / denom;

        float h[4];
        #pragma unroll
        for (int j = 0; j < 4; ++j)
            h[j] = fmaxf(acc[j] * inv + biasq[j], 0.f);
        float hd[H1];
        #pragma unroll
        for (int d = 0; d < H1; ++d)
            hd[d] = __shfl(h[d & 3], d >> 2, 64);
        if (lane < C2) {
            float al = bl2c, ar = br2c;
            #pragma unroll
            for (int d = 0; d < H1; ++d) {
                al = fmaf(hd[d], wl2c[d], al);
                ar = fmaf(hd[d], wr2c[d], ar);
            }
            xl2[(size_t)g * C2 + lane] = al;
            xr2[(size_t)g * C2 + lane] = ar;
        }
    }
}

// ---- layer-2 GAT gather (D=16): 4 nodes/wave, scalarized meta/addresses ----
__global__ __launch_bounds__(128) void k_gat2L(
        const int* __restrict__ sorted_g, const int* __restrict__ meta,
        const float* __restrict__ xl, const float* __restrict__ xr,
        const float* __restrict__ att, const float* __restrict__ bias,
        float* __restrict__ out) {
    int wv = (blockIdx.x * 128 + threadIdx.x) >> 6;
    int gbase = __builtin_amdgcn_readfirstlane(wv << 2);
    int lane = threadIdx.x & 63;
    int q = lane & 3, eo = lane >> 2;       // LPE=4, EPC=16

    float attq[4], biasq[4];
    #pragma unroll
    for (int j = 0; j < 4; ++j) { attq[j] = att[q * 4 + j]; biasq[j] = bias[q * 4 + j]; }

    #pragma unroll 2
    for (int i = 0; i < 4; ++i) {
        int g = gbase + i;
        int mt = meta[g];                   // s_load (g scalar)
        int deg = (mt & 0xFFFF) + 1;
        const int* sg = sorted_g + (size_t)(g >> 6) * CAP + (mt >> 16);

        float4 xr4 = ((const float4*)(xr + (size_t)g * C2))[q];
        float xrq[4] = {xr4.x, xr4.y, xr4.z, xr4.w};

        float denom = 0.f;
        float acc[4] = {0.f, 0.f, 0.f, 0.f};

        #pragma unroll
        for (int c = 0; c < 4; ++c) {
            if (c == 0 || deg > c * 16) {   // wave-uniform guard
                int e = c * 16 + eo;
                int src = (e > 0 && e < deg) ? sg[e - 1] : g;
                float4 v = ((const float4*)(xl + (size_t)src * C2))[q];
                float xv[4] = {v.x, v.y, v.z, v.w};
                float s = 0.f;
                #pragma unroll
                for (int j = 0; j < 4; ++j) {
                    float w = xv[j] + xrq[j];
                    w = fmaxf(w, NEG * w);
                    s = fmaf(attq[j], w, s);
                }
                s += __shfl_xor(s, 1, 64);
                s += __shfl_xor(s, 2, 64);
                float ex = (e < deg) ? __expf(s) : 0.f;
                denom += ex;
                #pragma unroll
                for (int j = 0; j < 4; ++j)
                    acc[j] = fmaf(ex, xv[j], acc[j]);
            }
        }
        for (int e0 = 64; e0 < deg; e0 += 16) {   // rare: deg > 64
            int e = e0 + eo;
            int src = (e < deg) ? sg[e - 1] : g;
            float4 v = ((const float4*)(xl + (size_t)src * C2))[q];
            float xv[4] = {v.x, v.y, v.z, v.w};
            float s = 0.f;
            #pragma unroll
            for (int j = 0; j < 4; ++j) {
                float w = xv[j] + xrq[j];
                w = fmaxf(w, NEG * w);
                s = fmaf(attq[j], w, s);
            }
            s += __shfl_xor(s, 1, 64);
            s += __shfl_xor(s, 2, 64);
            float ex = (e < deg) ? __expf(s) : 0.f;
            denom += ex;
            #pragma unroll
            for (int j = 0; j < 4; ++j)
                acc[j] = fmaf(ex, xv[j], acc[j]);
        }

        #pragma unroll
        for (int off = 4; off < 64; off <<= 1) {
            denom += __shfl_xor(denom, off, 64);
            #pragma unroll
            for (int j = 0; j < 4; ++j)
                acc[j] += __shfl_xor(acc[j], off, 64);
        }
        float inv = 1.f / denom;

        if (eo == 0) {
            float4 r;
            r.x = acc[0] * inv + biasq[0];
            r.y = acc[1] * inv + biasq[1];
            r.z = acc[2] * inv + biasq[2];
            r.w = acc[3] * inv + biasq[3];
            ((float4*)(out + (size_t)g * C2))[q] = r;
        }
    }
}

extern "C" void kernel_launch(void* const* d_in, const int* in_sizes, int n_in,
                              void* d_out, int out_size, void* d_ws, size_t ws_size,
                              hipStream_t stream) {
    const float* x     = (const float*)d_in[0];
    const int*   ei    = (const int*)d_in[1];
    const float* Wl1   = (const float*)d_in[2];
    const float* bl1   = (const float*)d_in[3];
    const float* Wr1   = (const float*)d_in[4];
    const float* br1   = (const float*)d_in[5];
    const float* att1  = (const float*)d_in[6];
    const float* bias1 = (const float*)d_in[7];
    const float* Wl2   = (const float*)d_in[8];
    const float* bl2   = (const float*)d_in[9];
    const float* Wr2   = (const float*)d_in[10];
    const float* br2   = (const float*)d_in[11];
    const float* att2  = (const float*)d_in[12];
    const float* bias2 = (const float*)d_in[13];
    float* out = (float*)d_out;

    // workspace layout
    int* bedges = (int*)d_ws;                        // NBP*CAP (sorted in-place)
    int* gcur1  = bedges + (size_t)NBP * CAP;        // 32
    int* gcur2  = gcur1 + SB;                        // NBP
    int* meta   = gcur2 + NBP;                       // NBP*64
    float* xl1  = (float*)(meta + NBP * BKT);        // NN*H1
    float* xr1  = xl1 + (size_t)NN * H1;             // NN*H1
    int* sup1   = (int*)(xr1 + (size_t)NN * H1);     // SB*SCAP (14.08 MB)
    float* xl2  = (float*)sup1;                      // overlay: sup1 dead after k_p2
    float* xr2  = xl2 + (size_t)NN * C2;             // NN*C2

    hipMemsetAsync(gcur1, 0, (SB + NBP) * sizeof(int), stream);

    k_a<<<P1B + LINB, 512, 0, stream>>>(x, Wl1, bl1, Wr1, br1, xl1, xr1,
                                        ei, gcur1, sup1);
    k_p2<<<1024, 512, 0, stream>>>(sup1, gcur1, gcur2, bedges);
    k_sortgat1<<<NB, 256, 0, stream>>>(bedges, gcur2, meta, xl1, xr1, att1, bias1,
                                       Wl2, bl2, Wr2, br2, xl2, xr2);
    k_gat2L<<<12500, 128, 0, stream>>>(bedges, meta, xl2, xr2, att2, bias2, out);
}

// Round 9
// 162.208 us; speedup vs baseline: 1.3355x; 1.0508x over previous
//
#include <hip/hip_runtime.h>

#define NN 100000
#define NE 3200000
#define FIN 256
#define H1 8
#define C2 16
#define NEG 0.2f

#define BKT 64                        // dst nodes per fine bucket
#define NB 1563                       // fine buckets with real nodes
#define NBP 1568                      // padded fine buckets (32 supers * 49)
#define CAP 2560                      // max edges per fine bucket (mean 2048)
#define SB 32                         // super-buckets
#define SBN 3136                      // nodes per super (49 * 64)
#define FPS 49                        // fine buckets per super
#define SCAP 110000                   // super region capacity (mean 100352)
#define P1B 1024                      // partition-1 logical blocks
#define EPB1 3125                     // NE / P1B
#define LINB 782                      // lin1 logical blocks (128 nodes each)
#define P2CAP 3520                    // >= max super slice

// ---- fused front kernel: role by blockIdx%7 (3 lin : 4 p1, coprime to 8 XCDs)
__global__ __launch_bounds__(512) void k_b(
        const float* __restrict__ x,
        const float* __restrict__ Wl, const float* __restrict__ bl,
        const float* __restrict__ Wr, const float* __restrict__ br,
        float* __restrict__ xl1, float* __restrict__ xr1,
        const int* __restrict__ ei,
        int* __restrict__ gcur1, int* __restrict__ sup1) {
    __shared__ int smem[6144];         // 24 KB shared by both roles
    int tid = threadIdx.x;
    int m = blockIdx.x % 7, d = blockIdx.x / 7;

    if (m >= 3) {
        // ---------------- partition stage 1 ----------------
        int p1 = d * 4 + (m - 3);
        if (p1 >= P1B) return;
        int* buf  = smem;              // EPB1
        int* cnt  = smem + EPB1;
        int* nb   = cnt + SB;
        int* cnt2 = nb + SB;
        int* gb   = cnt2 + SB;
        int base = p1 * EPB1;
        if (tid < SB) { cnt[tid] = 0; cnt2[tid] = 0; }
        int es[7], ed[7];
        #pragma unroll
        for (int r = 0; r < 7; ++r) {
            int i = tid + r * 512;
            if (i < EPB1) { es[r] = ei[base + i]; ed[r] = ei[NE + base + i]; }
        }
        __syncthreads();
        #pragma unroll
        for (int r = 0; r < 7; ++r) {
            int i = tid + r * 512;
            if (i < EPB1) atomicAdd(&cnt[ed[r] / SBN], 1);
        }
        __syncthreads();
        if (tid < SB) {                // scan + global reserve
            int v = cnt[tid], inc = v;
            #pragma unroll
            for (int off = 1; off < SB; off <<= 1) {
                int u = __shfl_up(inc, off, 64);
                if (tid >= off) inc += u;
            }
            nb[tid] = inc - v;
            gb[tid] = atomicAdd(&gcur1[tid], v);
        }
        __syncthreads();
        #pragma unroll
        for (int r = 0; r < 7; ++r) {
            int i = tid + r * 512;
            if (i < EPB1) {
                int s = ed[r] / SBN;
                int rr = ed[r] - s * SBN;
                int k = atomicAdd(&cnt2[s], 1);
                buf[nb[s] + k] = (rr << 17) | es[r];
            }
        }
        __syncthreads();
        for (int s = 0; s < SB; ++s) { // coalesced run flush
            int c = cnt[s], b = gb[s], o = nb[s];
            size_t dbase = (size_t)s * SCAP + b;
            for (int i = tid; i < c; i += 512)
                if (b + i < SCAP) sup1[dbase + i] = buf[o + i];
        }
    } else {
        // ------- layer-1 linear, GEMM-shaped: 4 lanes per node, W in LDS ----
        int lb = d * 3 + m;
        if (lb >= LINB) return;
        float* wlds = (float*)smem;    // [2][256][12]
        // stage weights: thread t -> one row of Wl (t<256) or Wr
        if (tid < 512) {
            int mat = tid >> 8, row = tid & 255;
            const float4* src = (const float4*)((mat ? Wr : Wl) + row * 8);
            float4 a = src[0], b4 = src[1];
            float* dst = wlds + mat * 3072 + row * 12;
            *(float4*)dst = a;
            *(float4*)(dst + 4) = b4;
        }
        __syncthreads();

        int lane = tid & 63;
        int w    = tid >> 6;                // wave 0..7 -> 16 nodes each
        int nloc = lane >> 2, q = lane & 3; // 4 lanes per node
        int node = lb * 128 + w * 16 + nloc;
        int nc   = node < NN ? node : NN - 1;

        float accl[8] = {0,0,0,0,0,0,0,0}, accr[8] = {0,0,0,0,0,0,0,0};
        const float* xrow = x + (size_t)nc * FIN;
        #pragma unroll 4
        for (int j = 0; j < 16; ++j) {
            float4 xv = *(const float4*)(xrow + j * 16 + q * 4);
            float xf[4] = {xv.x, xv.y, xv.z, xv.w};
            int k0 = j * 16 + q * 4;
            #pragma unroll
            for (int r = 0; r < 4; ++r) {
                const float* wr_l = wlds + (k0 + r) * 12;
                const float* wr_r = wr_l + 3072;
                float4 wl0 = *(const float4*)wr_l;
                float4 wl1 = *(const float4*)(wr_l + 4);
                float4 wr0 = *(const float4*)wr_r;
                float4 wr1 = *(const float4*)(wr_r + 4);
                accl[0] = fmaf(xf[r], wl0.x, accl[0]);
                accl[1] = fmaf(xf[r], wl0.y, accl[1]);
                accl[2] = fmaf(xf[r], wl0.z, accl[2]);
                accl[3] = fmaf(xf[r], wl0.w, accl[3]);
                accl[4] = fmaf(xf[r], wl1.x, accl[4]);
                accl[5] = fmaf(xf[r], wl1.y, accl[5]);
                accl[6] = fmaf(xf[r], wl1.z, accl[6]);
                accl[7] = fmaf(xf[r], wl1.w, accl[7]);
                accr[0] = fmaf(xf[r], wr0.x, accr[0]);
                accr[1] = fmaf(xf[r], wr0.y, accr[1]);
                accr[2] = fmaf(xf[r], wr0.z, accr[2]);
                accr[3] = fmaf(xf[r], wr0.w, accr[3]);
                accr[4] = fmaf(xf[r], wr1.x, accr[4]);
                accr[5] = fmaf(xf[r], wr1.y, accr[5]);
                accr[6] = fmaf(xf[r], wr1.z, accr[6]);
                accr[7] = fmaf(xf[r], wr1.w, accr[7]);
            }
        }
        // allreduce across the 4 k-lanes of this node
        #pragma unroll
        for (int off = 1; off < 4; off <<= 1) {
            #pragma unroll
            for (int h = 0; h < 8; ++h) {
                accl[h] += __shfl_xor(accl[h], off, 64);
                accr[h] += __shfl_xor(accr[h], off, 64);
            }
        }
        // lane q writes float4 segment q of [accl(8) | accr(8)] + bias
        if (node < NN) {
            const float* bsrc = (q < 2) ? bl : br;
            float4 bv = ((const float4*)bsrc)[q & 1];
            float* ap = (q & 2) ? accr : accl;
            int o = (q & 1) * 4;
            float4 rv;
            rv.x = ap[o + 0] + bv.x;
            rv.y = ap[o + 1] + bv.y;
            rv.z = ap[o + 2] + bv.z;
            rv.w = ap[o + 3] + bv.w;
            float* dst = ((q < 2) ? xl1 : xr1) + (size_t)node * H1 + (q & 1) * 4;
            *(float4*)dst = rv;
        }
    }
}

// ---- partition stage 2: super slice -> 49 fine buckets (32 slices/super) ---
__global__ __launch_bounds__(512) void k_p2(const int* __restrict__ sup1,
                                            const int* __restrict__ gcur1,
                                            int* __restrict__ gcur2,
                                            int* __restrict__ bedges) {
    __shared__ int buf[P2CAP];
    __shared__ int cnt[FPS], nb[FPS], cnt2[FPS], gb[FPS];
    int s   = blockIdx.x >> 5;
    int sub = blockIdx.x & 31;
    int tid = threadIdx.x;
    int total = gcur1[s]; if (total > SCAP) total = SCAP;
    int beg = (int)((long)total * sub / 32);
    int end = (int)((long)total * (sub + 1) / 32);
    int n = end - beg;
    const int* sp = sup1 + (size_t)s * SCAP + beg;
    if (tid < FPS) { cnt[tid] = 0; cnt2[tid] = 0; }
    int pk[7];
    #pragma unroll
    for (int r = 0; r < 7; ++r) {
        int i = tid + r * 512;
        if (i < n) pk[r] = sp[i];
    }
    __syncthreads();
    #pragma unroll
    for (int r = 0; r < 7; ++r) {
        int i = tid + r * 512;
        if (i < n) atomicAdd(&cnt[(pk[r] >> 17) >> 6], 1);
    }
    __syncthreads();
    if (tid < 64) {
        int v = (tid < FPS) ? cnt[tid] : 0, inc = v;
        #pragma unroll
        for (int off = 1; off < 64; off <<= 1) {
            int u = __shfl_up(inc, off, 64);
            if (tid >= off) inc += u;
        }
        if (tid < FPS) {
            nb[tid] = inc - v;
            gb[tid] = atomicAdd(&gcur2[s * FPS + tid], v);
        }
    }
    __syncthreads();
    #pragma unroll
    for (int r = 0; r < 7; ++r) {
        int i = tid + r * 512;
        if (i < n) {
            int fb = (pk[r] >> 17) >> 6;
            int k = atomicAdd(&cnt2[fb], 1);
            buf[nb[fb] + k] = (((pk[r] >> 17) & 63) << 17) | (pk[r] & 0x1FFFF);
        }
    }
    __syncthreads();
    for (int fb = 0; fb < FPS; ++fb) {
        int c = cnt[fb], b = gb[fb], o = nb[fb];
        size_t dbase = (size_t)(s * FPS + fb) * CAP + b;
        for (int i = tid; i < c; i += 512)
            if (b + i < CAP) bedges[dbase + i] = buf[o + i];
    }
}

// ---- fused: per-bucket counting sort + layer-1 GAT + mid GEMM (512 thr) ----
__global__ __launch_bounds__(512) void k_sortgat1(
        int* __restrict__ bedges, const int* __restrict__ gcur2,
        int* __restrict__ meta,
        const float* __restrict__ xl, const float* __restrict__ xr,
        const float* __restrict__ att, const float* __restrict__ bias,
        const float* __restrict__ Wl2, const float* __restrict__ bl2,
        const float* __restrict__ Wr2, const float* __restrict__ br2,
        float* __restrict__ xl2, float* __restrict__ xr2) {
    __shared__ int sorted[CAP];
    __shared__ int hist[BKT], nbase[BKT], scnt[BKT];
    int bkt = blockIdx.x;
    int tid = threadIdx.x;
    int ecnt = gcur2[bkt]; if (ecnt > CAP) ecnt = CAP;
    int* be = bedges + (size_t)bkt * CAP;
    if (tid < BKT) { hist[tid] = 0; scnt[tid] = 0; }
    __syncthreads();
    for (int i = tid; i < ecnt; i += 512)
        atomicAdd(&hist[be[i] >> 17], 1);
    __syncthreads();
    if (tid < BKT) {                   // wave-parallel exclusive scan
        int v = hist[tid], inc = v;
        #pragma unroll
        for (int off = 1; off < 64; off <<= 1) {
            int u = __shfl_up(inc, off, 64);
            if (tid >= off) inc += u;
        }
        nbase[tid] = inc - v;
        meta[bkt * BKT + tid] = ((inc - v) << 16) | v;   // for layer 2
    }
    __syncthreads();
    for (int i = tid; i < ecnt; i += 512) {
        int pk = be[i];
        int dl = pk >> 17;
        int r = atomicAdd(&scnt[dl], 1);
        sorted[nbase[dl] + r] = pk & 0x1FFFF;
    }
    __syncthreads();
    for (int i = tid; i < ecnt; i += 512)   // writeback for layer 2
        be[i] = sorted[i];

    // ---------------- layer-1 GAT (D=8) + mid GEMM ----------------
    int wave = tid >> 6, lane = tid & 63;
    int q = lane & 1, eo = lane >> 1;       // LPE=2, EPC=32

    float attq[4], biasq[4];
    #pragma unroll
    for (int j = 0; j < 4; ++j) { attq[j] = att[q * 4 + j]; biasq[j] = bias[q * 4 + j]; }
    float wl2c[H1], wr2c[H1], bl2c = 0.f, br2c = 0.f;
    if (lane < C2) {
        #pragma unroll
        for (int d = 0; d < H1; ++d) {
            wl2c[d] = Wl2[d * C2 + lane];
            wr2c[d] = Wr2[d * C2 + lane];
        }
        bl2c = bl2[lane]; br2c = br2[lane];
    }

    for (int n = wave; n < BKT; n += 8) {
        int g = bkt * BKT + n;
        if (g >= NN) break;
        int deg = hist[n] + 1;              // + self-loop (e==0)
        int nb_ = nbase[n];

        float4 xr4 = ((const float4*)(xr + (size_t)g * H1))[q];
        float xrq[4] = {xr4.x, xr4.y, xr4.z, xr4.w};

        float denom = 0.f;
        float acc[4] = {0.f, 0.f, 0.f, 0.f};

        #pragma unroll
        for (int c = 0; c < 2; ++c) {
            if (c == 0 || deg > 32) {
                int e = c * 32 + eo;
                int src = (e > 0 && e < deg) ? sorted[nb_ + e - 1] : g;
                float4 v = ((const float4*)(xl + (size_t)src * H1))[q];
                float xv[4] = {v.x, v.y, v.z, v.w};
                float s = 0.f;
                #pragma unroll
                for (int j = 0; j < 4; ++j) {
                    float w = xv[j] + xrq[j];
                    w = fmaxf(w, NEG * w);
                    s = fmaf(attq[j], w, s);
                }
                s += __shfl_xor(s, 1, 64);
                float ex = (e < deg) ? __expf(s) : 0.f;
                denom += ex;
                #pragma unroll
                for (int j = 0; j < 4; ++j)
                    acc[j] = fmaf(ex, xv[j], acc[j]);
            }
        }
        for (int e0 = 64; e0 < deg; e0 += 32) {   // rare: deg > 64
            int e = e0 + eo;
            int src = (e < deg) ? sorted[nb_ + e - 1] : g;
            float4 v = ((const float4*)(xl + (size_t)src * H1))[q];
            float xv[4] = {v.x, v.y, v.z, v.w};
            float s = 0.f;
            #pragma unroll
            for (int j = 0; j < 4; ++j) {
                float w = xv[j] + xrq[j];
                w = fmaxf(w, NEG * w);
                s = fmaf(attq[j], w, s);
            }
            s += __shfl_xor(s, 1, 64);
            float ex = (e < deg) ? __expf(s) : 0.f;
            denom += ex;
            #pragma unroll
            for (int j = 0; j < 4; ++j)
                acc[j] = fmaf(ex, xv[j], acc[j]);
        }

        #pragma unroll
        for (int off = 2; off < 64; off <<= 1) {
            denom += __shfl_xor(denom, off, 64);
            #pragma unroll
            for (int j = 0; j < 4; ++j)
                acc[j] += __shfl_xor(acc[j], off, 64);
        }
        float inv = 1.f / denom;

        float h[4];
        #pragma unroll
        for (int j = 0; j < 4; ++j)
            h[j] = fmaxf(acc[j] * inv + biasq[j], 0.f);
        float hd[H1];
        #pragma unroll
        for (int d = 0; d < H1; ++d)
            hd[d] = __shfl(h[d & 3], d >> 2, 64);
        if (lane < C2) {
            float al = bl2c, ar = br2c;
            #pragma unroll
            for (int d = 0; d < H1; ++d) {
                al = fmaf(hd[d], wl2c[d], al);
                ar = fmaf(hd[d], wr2c[d], ar);
            }
            xl2[(size_t)g * C2 + lane] = al;
            xr2[(size_t)g * C2 + lane] = ar;
        }
    }
}

// ---- layer-2 GAT gather (D=16): 4 nodes/wave, scalarized meta/addresses ----
__global__ __launch_bounds__(128) void k_gat2L(
        const int* __restrict__ sorted_g, const int* __restrict__ meta,
        const float* __restrict__ xl, const float* __restrict__ xr,
        const float* __restrict__ att, const float* __restrict__ bias,
        float* __restrict__ out) {
    int wv = (blockIdx.x * 128 + threadIdx.x) >> 6;
    int gbase = __builtin_amdgcn_readfirstlane(wv << 2);
    int lane = threadIdx.x & 63;
    int q = lane & 3, eo = lane >> 2;       // LPE=4, EPC=16

    float attq[4], biasq[4];
    #pragma unroll
    for (int j = 0; j < 4; ++j) { attq[j] = att[q * 4 + j]; biasq[j] = bias[q * 4 + j]; }

    #pragma unroll 2
    for (int i = 0; i < 4; ++i) {
        int g = gbase + i;
        int mt = meta[g];                   // s_load (g scalar)
        int deg = (mt & 0xFFFF) + 1;
        const int* sg = sorted_g + (size_t)(g >> 6) * CAP + (mt >> 16);

        float4 xr4 = ((const float4*)(xr + (size_t)g * C2))[q];
        float xrq[4] = {xr4.x, xr4.y, xr4.z, xr4.w};

        float denom = 0.f;
        float acc[4] = {0.f, 0.f, 0.f, 0.f};

        #pragma unroll
        for (int c = 0; c < 4; ++c) {
            if (c == 0 || deg > c * 16) {   // wave-uniform guard
                int e = c * 16 + eo;
                int src = (e > 0 && e < deg) ? sg[e - 1] : g;
                float4 v = ((const float4*)(xl + (size_t)src * C2))[q];
                float xv[4] = {v.x, v.y, v.z, v.w};
                float s = 0.f;
                #pragma unroll
                for (int j = 0; j < 4; ++j) {
                    float w = xv[j] + xrq[j];
                    w = fmaxf(w, NEG * w);
                    s = fmaf(attq[j], w, s);
                }
                s += __shfl_xor(s, 1, 64);
                s += __shfl_xor(s, 2, 64);
                float ex = (e < deg) ? __expf(s) : 0.f;
                denom += ex;
                #pragma unroll
                for (int j = 0; j < 4; ++j)
                    acc[j] = fmaf(ex, xv[j], acc[j]);
            }
        }
        for (int e0 = 64; e0 < deg; e0 += 16) {   // rare: deg > 64
            int e = e0 + eo;
            int src = (e < deg) ? sg[e - 1] : g;
            float4 v = ((const float4*)(xl + (size_t)src * C2))[q];
            float xv[4] = {v.x, v.y, v.z, v.w};
            float s = 0.f;
            #pragma unroll
            for (int j = 0; j < 4; ++j) {
                float w = xv[j] + xrq[j];
                w = fmaxf(w, NEG * w);
                s = fmaf(attq[j], w, s);
            }
            s += __shfl_xor(s, 1, 64);
            s += __shfl_xor(s, 2, 64);
            float ex = (e < deg) ? __expf(s) : 0.f;
            denom += ex;
            #pragma unroll
            for (int j = 0; j < 4; ++j)
                acc[j] = fmaf(ex, xv[j], acc[j]);
        }

        #pragma unroll
        for (int off = 4; off < 64; off <<= 1) {
            denom += __shfl_xor(denom, off, 64);
            #pragma unroll
            for (int j = 0; j < 4; ++j)
                acc[j] += __shfl_xor(acc[j], off, 64);
        }
        float inv = 1.f / denom;

        if (eo == 0) {
            float4 r;
            r.x = acc[0] * inv + biasq[0];
            r.y = acc[1] * inv + biasq[1];
            r.z = acc[2] * inv + biasq[2];
            r.w = acc[3] * inv + biasq[3];
            ((float4*)(out + (size_t)g * C2))[q] = r;
        }
    }
}

extern "C" void kernel_launch(void* const* d_in, const int* in_sizes, int n_in,
                              void* d_out, int out_size, void* d_ws, size_t ws_size,
                              hipStream_t stream) {
    const float* x     = (const float*)d_in[0];
    const int*   ei    = (const int*)d_in[1];
    const float* Wl1   = (const float*)d_in[2];
    const float* bl1   = (const float*)d_in[3];
    const float* Wr1   = (const float*)d_in[4];
    const float* br1   = (const float*)d_in[5];
    const float* att1  = (const float*)d_in[6];
    const float* bias1 = (const float*)d_in[7];
    const float* Wl2   = (const float*)d_in[8];
    const float* bl2   = (const float*)d_in[9];
    const float* Wr2   = (const float*)d_in[10];
    const float* br2   = (const float*)d_in[11];
    const float* att2  = (const float*)d_in[12];
    const float* bias2 = (const float*)d_in[13];
    float* out = (float*)d_out;

    // workspace layout
    int* bedges = (int*)d_ws;                        // NBP*CAP (sorted in-place)
    int* gcur1  = bedges + (size_t)NBP * CAP;        // 32
    int* gcur2  = gcur1 + SB;                        // NBP
    int* meta   = gcur2 + NBP;                       // NBP*64
    float* xl1  = (float*)(meta + NBP * BKT);        // NN*H1
    float* xr1  = xl1 + (size_t)NN * H1;             // NN*H1
    int* sup1   = (int*)(xr1 + (size_t)NN * H1);     // SB*SCAP (14.08 MB)
    float* xl2  = (float*)sup1;                      // overlay: sup1 dead after k_p2
    float* xr2  = xl2 + (size_t)NN * C2;             // NN*C2

    hipMemsetAsync(gcur1, 0, (SB + NBP) * sizeof(int), stream);

    k_b<<<1827, 512, 0, stream>>>(x, Wl1, bl1, Wr1, br1, xl1, xr1,
                                  ei, gcur1, sup1);
    k_p2<<<1024, 512, 0, stream>>>(sup1, gcur1, gcur2, bedges);
    k_sortgat1<<<NB, 512, 0, stream>>>(bedges, gcur2, meta, xl1, xr1, att1, bias1,
                                       Wl2, bl2, Wr2, br2, xl2, xr2);
    k_gat2L<<<12500, 128, 0, stream>>>(bedges, meta, xl2, xr2, att2, bias2, out);
}

// Round 10
// 158.625 us; speedup vs baseline: 1.3657x; 1.0226x over previous
//
#include <hip/hip_runtime.h>

#define NN 100000
#define NE 3200000
#define FIN 256
#define H1 8
#define C2 16
#define NEG 0.2f

#define BKT 64                        // dst nodes per fine bucket
#define NB 1563                       // fine buckets with real nodes
#define NBP 1568                      // padded fine buckets (32 supers * 49)
#define CAP 2560                      // max edges per fine bucket (mean 2048)
#define SB 32                         // super-buckets
#define SBN 3136                      // nodes per super (49 * 64)
#define FPS 49                        // fine buckets per super
#define SCAP 110000                   // super region capacity (mean 100352)
#define P1B 1024                      // partition-1 logical blocks
#define EPB1 3125                     // NE / P1B
#define LINB 1563                     // lin logical blocks (64 nodes each)
#define P2CAP 3520                    // >= max super slice
#define XR 132                        // x-tile row stride (16B-aligned, floor-conflict)

// ---- fused front kernel: role by blockIdx%5 (3 lin : 2 p1) ----
__global__ __launch_bounds__(512) void k_b(
        const float* __restrict__ x,
        const float* __restrict__ Wl, const float* __restrict__ bl,
        const float* __restrict__ Wr, const float* __restrict__ br,
        float* __restrict__ xl1, float* __restrict__ xr1,
        const int* __restrict__ ei,
        int* __restrict__ gcur1, int* __restrict__ sup1) {
    __shared__ int smem[10240];        // 40 KB shared by both roles
    int tid = threadIdx.x;
    int m = blockIdx.x % 5, d = blockIdx.x / 5;

    if (m >= 3) {
        // ---------------- partition stage 1 ----------------
        int p1 = d * 2 + (m - 3);
        if (p1 >= P1B) return;
        int* buf  = smem;              // EPB1
        int* cnt  = smem + EPB1;
        int* nb   = cnt + SB;
        int* cnt2 = nb + SB;
        int* gb   = cnt2 + SB;
        int base = p1 * EPB1;
        if (tid < SB) { cnt[tid] = 0; cnt2[tid] = 0; }
        int es[7], ed[7];
        #pragma unroll
        for (int r = 0; r < 7; ++r) {
            int i = tid + r * 512;
            if (i < EPB1) { es[r] = ei[base + i]; ed[r] = ei[NE + base + i]; }
        }
        __syncthreads();
        #pragma unroll
        for (int r = 0; r < 7; ++r) {
            int i = tid + r * 512;
            if (i < EPB1) atomicAdd(&cnt[ed[r] / SBN], 1);
        }
        __syncthreads();
        if (tid < SB) {                // scan + global reserve
            int v = cnt[tid], inc = v;
            #pragma unroll
            for (int off = 1; off < SB; off <<= 1) {
                int u = __shfl_up(inc, off, 64);
                if (tid >= off) inc += u;
            }
            nb[tid] = inc - v;
            gb[tid] = atomicAdd(&gcur1[tid], v);
        }
        __syncthreads();
        #pragma unroll
        for (int r = 0; r < 7; ++r) {
            int i = tid + r * 512;
            if (i < EPB1) {
                int s = ed[r] / SBN;
                int rr = ed[r] - s * SBN;
                int k = atomicAdd(&cnt2[s], 1);
                buf[nb[s] + k] = (rr << 17) | es[r];
            }
        }
        __syncthreads();
        for (int s = 0; s < SB; ++s) { // coalesced run flush
            int c = cnt[s], b = gb[s], o = nb[s];
            size_t dbase = (size_t)s * SCAP + b;
            for (int i = tid; i < c; i += 512)
                if (b + i < SCAP) sup1[dbase + i] = buf[o + i];
        }
    } else {
        // ---- layer-1 linear: x tile in LDS (coalesced), weights via s_load
        int lb = d * 3 + m;            // 0..1562
        int blkNode = lb * 64;
        float* xf   = (float*)smem;    // [64][XR]  (8448 words)
        float* part = (float*)smem;    // reuse:  [8][64][20] (10240 words)
        int lane = tid & 63;
        int wq = __builtin_amdgcn_readfirstlane(tid >> 6);   // k-sixteenth 0..7

        float accl[8] = {0,0,0,0,0,0,0,0}, accr[8] = {0,0,0,0,0,0,0,0};

        #pragma unroll
        for (int ph = 0; ph < 2; ++ph) {
            __syncthreads();
            // stage half tile (64 rows x 128 cols), coalesced
            #pragma unroll
            for (int pass = 0; pass < 4; ++pass) {
                int i = tid + pass * 512;      // float4 index, 2048 total
                int row = i >> 5, c4 = i & 31;
                int node = blkNode + row; if (node >= NN) node = NN - 1;
                float4 v = *(const float4*)(x + (size_t)node * FIN + ph * 128 + c4 * 4);
                *(float4*)&xf[row * XR + c4 * 4] = v;
            }
            __syncthreads();
            int kbase = ph * 128 + wq * 16;
            const float* wlp = Wl + kbase * 8;     // scalar (wave-uniform)
            const float* wrp = Wr + kbase * 8;
            const float* xrow = &xf[lane * XR + wq * 16];
            #pragma unroll
            for (int jq = 0; jq < 4; ++jq) {
                float4 xv = *(const float4*)(xrow + jq * 4);
                float xa[4] = {xv.x, xv.y, xv.z, xv.w};
                #pragma unroll
                for (int r = 0; r < 4; ++r) {
                    int k = jq * 4 + r;
                    #pragma unroll
                    for (int h = 0; h < 8; ++h) {
                        accl[h] = fmaf(xa[r], wlp[k * 8 + h], accl[h]);
                        accr[h] = fmaf(xa[r], wrp[k * 8 + h], accr[h]);
                    }
                }
            }
        }
        __syncthreads();
        // write partials [8][64][20] (b128-aligned, floor throughput)
        float* pw = part + (size_t)(wq * 64 + lane) * 20;
        *(float4*)(pw)      = make_float4(accl[0], accl[1], accl[2], accl[3]);
        *(float4*)(pw + 4)  = make_float4(accl[4], accl[5], accl[6], accl[7]);
        *(float4*)(pw + 8)  = make_float4(accr[0], accr[1], accr[2], accr[3]);
        *(float4*)(pw + 12) = make_float4(accr[4], accr[5], accr[6], accr[7]);
        __syncthreads();
        // reduce 8 waves: thread -> (node = tid>>3, out-pair p = tid&7)
        int n2 = tid >> 3, p = tid & 7;
        float s0 = 0.f, s1 = 0.f;
        #pragma unroll
        for (int w2 = 0; w2 < 8; ++w2) {
            const float* pr = part + (size_t)(w2 * 64 + n2) * 20 + p * 2;
            s0 += pr[0]; s1 += pr[1];
        }
        int node = blkNode + n2;
        if (node < NN) {
            int o = p * 2;
            if (o < 8) {
                s0 += bl[o]; s1 += bl[o + 1];
                *(float2*)(xl1 + (size_t)node * H1 + o) = make_float2(s0, s1);
            } else {
                s0 += br[o - 8]; s1 += br[o - 7];
                *(float2*)(xr1 + (size_t)node * H1 + (o - 8)) = make_float2(s0, s1);
            }
        }
    }
}

// ---- partition stage 2: super slice -> 49 fine buckets (32 slices/super) ---
__global__ __launch_bounds__(512) void k_p2(const int* __restrict__ sup1,
                                            const int* __restrict__ gcur1,
                                            int* __restrict__ gcur2,
                                            int* __restrict__ bedges) {
    __shared__ int buf[P2CAP];
    __shared__ int cnt[FPS], nb[FPS], cnt2[FPS], gb[FPS];
    int s   = blockIdx.x >> 5;
    int sub = blockIdx.x & 31;
    int tid = threadIdx.x;
    int total = gcur1[s]; if (total > SCAP) total = SCAP;
    int beg = (int)((long)total * sub / 32);
    int end = (int)((long)total * (sub + 1) / 32);
    int n = end - beg;
    const int* sp = sup1 + (size_t)s * SCAP + beg;
    if (tid < FPS) { cnt[tid] = 0; cnt2[tid] = 0; }
    int pk[7];
    #pragma unroll
    for (int r = 0; r < 7; ++r) {
        int i = tid + r * 512;
        if (i < n) pk[r] = sp[i];
    }
    __syncthreads();
    #pragma unroll
    for (int r = 0; r < 7; ++r) {
        int i = tid + r * 512;
        if (i < n) atomicAdd(&cnt[(pk[r] >> 17) >> 6], 1);
    }
    __syncthreads();
    if (tid < 64) {
        int v = (tid < FPS) ? cnt[tid] : 0, inc = v;
        #pragma unroll
        for (int off = 1; off < 64; off <<= 1) {
            int u = __shfl_up(inc, off, 64);
            if (tid >= off) inc += u;
        }
        if (tid < FPS) {
            nb[tid] = inc - v;
            gb[tid] = atomicAdd(&gcur2[s * FPS + tid], v);
        }
    }
    __syncthreads();
    #pragma unroll
    for (int r = 0; r < 7; ++r) {
        int i = tid + r * 512;
        if (i < n) {
            int fb = (pk[r] >> 17) >> 6;
            int k = atomicAdd(&cnt2[fb], 1);
            buf[nb[fb] + k] = (((pk[r] >> 17) & 63) << 17) | (pk[r] & 0x1FFFF);
        }
    }
    __syncthreads();
    for (int fb = 0; fb < FPS; ++fb) {
        int c = cnt[fb], b = gb[fb], o = nb[fb];
        size_t dbase = (size_t)(s * FPS + fb) * CAP + b;
        for (int i = tid; i < c; i += 512)
            if (b + i < CAP) bedges[dbase + i] = buf[o + i];
    }
}

// ---- fused: per-bucket counting sort + layer-1 GAT + mid GEMM (512 thr) ----
__global__ __launch_bounds__(512) void k_sortgat1(
        int* __restrict__ bedges, const int* __restrict__ gcur2,
        int* __restrict__ meta,
        const float* __restrict__ xl, const float* __restrict__ xr,
        const float* __restrict__ att, const float* __restrict__ bias,
        const float* __restrict__ Wl2, const float* __restrict__ bl2,
        const float* __restrict__ Wr2, const float* __restrict__ br2,
        float* __restrict__ xl2, float* __restrict__ xr2) {
    __shared__ int sorted[CAP];
    __shared__ int hist[BKT], nbase[BKT], scnt[BKT];
    int bkt = blockIdx.x;
    int tid = threadIdx.x;
    int ecnt = gcur2[bkt]; if (ecnt > CAP) ecnt = CAP;
    int* be = bedges + (size_t)bkt * CAP;
    if (tid < BKT) { hist[tid] = 0; scnt[tid] = 0; }
    __syncthreads();
    for (int i = tid; i < ecnt; i += 512)
        atomicAdd(&hist[be[i] >> 17], 1);
    __syncthreads();
    if (tid < BKT) {                   // wave-parallel exclusive scan
        int v = hist[tid], inc = v;
        #pragma unroll
        for (int off = 1; off < 64; off <<= 1) {
            int u = __shfl_up(inc, off, 64);
            if (tid >= off) inc += u;
        }
        nbase[tid] = inc - v;
        meta[bkt * BKT + tid] = ((inc - v) << 16) | v;   // for layer 2
    }
    __syncthreads();
    for (int i = tid; i < ecnt; i += 512) {
        int pk = be[i];
        int dl = pk >> 17;
        int r = atomicAdd(&scnt[dl], 1);
        sorted[nbase[dl] + r] = pk & 0x1FFFF;
    }
    __syncthreads();
    for (int i = tid; i < ecnt; i += 512)   // writeback for layer 2
        be[i] = sorted[i];

    // ---------------- layer-1 GAT (D=8) + mid GEMM ----------------
    int wave = tid >> 6, lane = tid & 63;
    int q = lane & 1, eo = lane >> 1;       // LPE=2, EPC=32

    float attq[4], biasq[4];
    #pragma unroll
    for (int j = 0; j < 4; ++j) { attq[j] = att[q * 4 + j]; biasq[j] = bias[q * 4 + j]; }
    float wl2c[H1], wr2c[H1], bl2c = 0.f, br2c = 0.f;
    if (lane < C2) {
        #pragma unroll
        for (int d = 0; d < H1; ++d) {
            wl2c[d] = Wl2[d * C2 + lane];
            wr2c[d] = Wr2[d * C2 + lane];
        }
        bl2c = bl2[lane]; br2c = br2[lane];
    }

    for (int n = wave; n < BKT; n += 8) {
        int g = bkt * BKT + n;
        if (g >= NN) break;
        int deg = hist[n] + 1;              // + self-loop (e==0)
        int nb_ = nbase[n];

        float4 xr4 = ((const float4*)(xr + (size_t)g * H1))[q];
        float xrq[4] = {xr4.x, xr4.y, xr4.z, xr4.w};

        float denom = 0.f;
        float acc[4] = {0.f, 0.f, 0.f, 0.f};

        #pragma unroll
        for (int c = 0; c < 2; ++c) {
            if (c == 0 || deg > 32) {
                int e = c * 32 + eo;
                int src = (e > 0 && e < deg) ? sorted[nb_ + e - 1] : g;
                float4 v = ((const float4*)(xl + (size_t)src * H1))[q];
                float xv[4] = {v.x, v.y, v.z, v.w};
                float s = 0.f;
                #pragma unroll
                for (int j = 0; j < 4; ++j) {
                    float w = xv[j] + xrq[j];
                    w = fmaxf(w, NEG * w);
                    s = fmaf(attq[j], w, s);
                }
                s += __shfl_xor(s, 1, 64);
                float ex = (e < deg) ? __expf(s) : 0.f;
                denom += ex;
                #pragma unroll
                for (int j = 0; j < 4; ++j)
                    acc[j] = fmaf(ex, xv[j], acc[j]);
            }
        }
        for (int e0 = 64; e0 < deg; e0 += 32) {   // rare: deg > 64
            int e = e0 + eo;
            int src = (e < deg) ? sorted[nb_ + e - 1] : g;
            float4 v = ((const float4*)(xl + (size_t)src * H1))[q];
            float xv[4] = {v.x, v.y, v.z, v.w};
            float s = 0.f;
            #pragma unroll
            for (int j = 0; j < 4; ++j) {
                float w = xv[j] + xrq[j];
                w = fmaxf(w, NEG * w);
                s = fmaf(attq[j], w, s);
            }
            s += __shfl_xor(s, 1, 64);
            float ex = (e < deg) ? __expf(s) : 0.f;
            denom += ex;
            #pragma unroll
            for (int j = 0; j < 4; ++j)
                acc[j] = fmaf(ex, xv[j], acc[j]);
        }

        #pragma unroll
        for (int off = 2; off < 64; off <<= 1) {
            denom += __shfl_xor(denom, off, 64);
            #pragma unroll
            for (int j = 0; j < 4; ++j)
                acc[j] += __shfl_xor(acc[j], off, 64);
        }
        float inv = 1.f / denom;

        float h[4];
        #pragma unroll
        for (int j = 0; j < 4; ++j)
            h[j] = fmaxf(acc[j] * inv + biasq[j], 0.f);
        float hd[H1];
        #pragma unroll
        for (int d = 0; d < H1; ++d)
            hd[d] = __shfl(h[d & 3], d >> 2, 64);
        if (lane < C2) {
            float al = bl2c, ar = br2c;
            #pragma unroll
            for (int d = 0; d < H1; ++d) {
                al = fmaf(hd[d], wl2c[d], al);
                ar = fmaf(hd[d], wr2c[d], ar);
            }
            xl2[(size_t)g * C2 + lane] = al;
            xr2[(size_t)g * C2 + lane] = ar;
        }
    }
}

// ---- layer-2 GAT gather (D=16): 4 nodes/wave, scalarized meta/addresses ----
__global__ __launch_bounds__(128) void k_gat2L(
        const int* __restrict__ sorted_g, const int* __restrict__ meta,
        const float* __restrict__ xl, const float* __restrict__ xr,
        const float* __restrict__ att, const float* __restrict__ bias,
        float* __restrict__ out) {
    int wv = (blockIdx.x * 128 + threadIdx.x) >> 6;
    int gbase = __builtin_amdgcn_readfirstlane(wv << 2);
    int lane = threadIdx.x & 63;
    int q = lane & 3, eo = lane >> 2;       // LPE=4, EPC=16

    float attq[4], biasq[4];
    #pragma unroll
    for (int j = 0; j < 4; ++j) { attq[j] = att[q * 4 + j]; biasq[j] = bias[q * 4 + j]; }

    #pragma unroll 2
    for (int i = 0; i < 4; ++i) {
        int g = gbase + i;
        int mt = meta[g];                   // s_load (g scalar)
        int deg = (mt & 0xFFFF) + 1;
        const int* sg = sorted_g + (size_t)(g >> 6) * CAP + (mt >> 16);

        float4 xr4 = ((const float4*)(xr + (size_t)g * C2))[q];
        float xrq[4] = {xr4.x, xr4.y, xr4.z, xr4.w};

        float denom = 0.f;
        float acc[4] = {0.f, 0.f, 0.f, 0.f};

        #pragma unroll
        for (int c = 0; c < 4; ++c) {
            if (c == 0 || deg > c * 16) {   // wave-uniform guard
                int e = c * 16 + eo;
                int src = (e > 0 && e < deg) ? sg[e - 1] : g;
                float4 v = ((const float4*)(xl + (size_t)src * C2))[q];
                float xv[4] = {v.x, v.y, v.z, v.w};
                float s = 0.f;
                #pragma unroll
                for (int j = 0; j < 4; ++j) {
                    float w = xv[j] + xrq[j];
                    w = fmaxf(w, NEG * w);
                    s = fmaf(attq[j], w, s);
                }
                s += __shfl_xor(s, 1, 64);
                s += __shfl_xor(s, 2, 64);
                float ex = (e < deg) ? __expf(s) : 0.f;
                denom += ex;
                #pragma unroll
                for (int j = 0; j < 4; ++j)
                    acc[j] = fmaf(ex, xv[j], acc[j]);
            }
        }
        for (int e0 = 64; e0 < deg; e0 += 16) {   // rare: deg > 64
            int e = e0 + eo;
            int src = (e < deg) ? sg[e - 1] : g;
            float4 v = ((const float4*)(xl + (size_t)src * C2))[q];
            float xv[4] = {v.x, v.y, v.z, v.w};
            float s = 0.f;
            #pragma unroll
            for (int j = 0; j < 4; ++j) {
                float w = xv[j] + xrq[j];
                w = fmaxf(w, NEG * w);
                s = fmaf(attq[j], w, s);
            }
            s += __shfl_xor(s, 1, 64);
            s += __shfl_xor(s, 2, 64);
            float ex = (e < deg) ? __expf(s) : 0.f;
            denom += ex;
            #pragma unroll
            for (int j = 0; j < 4; ++j)
                acc[j] = fmaf(ex, xv[j], acc[j]);
        }

        #pragma unroll
        for (int off = 4; off < 64; off <<= 1) {
            denom += __shfl_xor(denom, off, 64);
            #pragma unroll
            for (int j = 0; j < 4; ++j)
                acc[j] += __shfl_xor(acc[j], off, 64);
        }
        float inv = 1.f / denom;

        if (eo == 0) {
            float4 r;
            r.x = acc[0] * inv + biasq[0];
            r.y = acc[1] * inv + biasq[1];
            r.z = acc[2] * inv + biasq[2];
            r.w = acc[3] * inv + biasq[3];
            ((float4*)(out + (size_t)g * C2))[q] = r;
        }
    }
}

extern "C" void kernel_launch(void* const* d_in, const int* in_sizes, int n_in,
                              void* d_out, int out_size, void* d_ws, size_t ws_size,
                              hipStream_t stream) {
    const float* x     = (const float*)d_in[0];
    const int*   ei    = (const int*)d_in[1];
    const float* Wl1   = (const float*)d_in[2];
    const float* bl1   = (const float*)d_in[3];
    const float* Wr1   = (const float*)d_in[4];
    const float* br1   = (const float*)d_in[5];
    const float* att1  = (const float*)d_in[6];
    const float* bias1 = (const float*)d_in[7];
    const float* Wl2   = (const float*)d_in[8];
    const float* bl2   = (const float*)d_in[9];
    const float* Wr2   = (const float*)d_in[10];
    const float* br2   = (const float*)d_in[11];
    const float* att2  = (const float*)d_in[12];
    const float* bias2 = (const float*)d_in[13];
    float* out = (float*)d_out;

    // workspace layout
    int* bedges = (int*)d_ws;                        // NBP*CAP (sorted in-place)
    int* gcur1  = bedges + (size_t)NBP * CAP;        // 32
    int* gcur2  = gcur1 + SB;                        // NBP
    int* meta   = gcur2 + NBP;                       // NBP*64
    float* xl1  = (float*)(meta + NBP * BKT);        // NN*H1
    float* xr1  = xl1 + (size_t)NN * H1;             // NN*H1
    int* sup1   = (int*)(xr1 + (size_t)NN * H1);     // SB*SCAP (14.08 MB)
    float* xl2  = (float*)sup1;                      // overlay: sup1 dead after k_p2
    float* xr2  = xl2 + (size_t)NN * C2;             // NN*C2

    hipMemsetAsync(gcur1, 0, (SB + NBP) * sizeof(int), stream);

    k_b<<<2605, 512, 0, stream>>>(x, Wl1, bl1, Wr1, br1, xl1, xr1,
                                  ei, gcur1, sup1);
    k_p2<<<1024, 512, 0, stream>>>(sup1, gcur1, gcur2, bedges);
    k_sortgat1<<<NB, 512, 0, stream>>>(bedges, gcur2, meta, xl1, xr1, att1, bias1,
                                       Wl2, bl2, Wr2, br2, xl2, xr2);
    k_gat2L<<<12500, 128, 0, stream>>>(bedges, meta, xl2, xr2, att2, bias2, out);
}